// Round 9
// baseline (130.152 us; speedup 1.0000x reference)
//
#include <hip/hip_runtime.h>

typedef unsigned short u16;
typedef unsigned int u32;
typedef __attribute__((ext_vector_type(8))) short short8;
typedef __attribute__((ext_vector_type(4))) float f32x4;

__device__ __forceinline__ float bf2f(u16 h){ return __builtin_bit_cast(float, ((u32)h) << 16); }
__device__ __forceinline__ u16 f2bf(float f){
  u32 u = __builtin_bit_cast(u32, f);
  u32 r = u + 0x7fffu + ((u >> 16) & 1u);
  return (u16)(r >> 16);
}
// byte offset of channel-octet `co` of tile-pixel `px` in a swizzled [px][256ch] bf16 LDS tile
__device__ __forceinline__ int swzb(int px, int co){
  return px * 512 + ((co * 16) ^ ((((px & 7) ^ ((px >> 3) * 3)) & 7) << 4));
}
// unpack 8 interleaved (h|l<<16) channel words (2 uint4) -> vh (8 bf16 hi), vl (8 bf16 lo)
__device__ __forceinline__ void unpk(const uint4 A, const uint4 B, uint4& vh, uint4& vl){
  vh.x = (A.x & 0xffffu) | (A.y << 16);  vl.x = (A.x >> 16) | (A.y & 0xffff0000u);
  vh.y = (A.z & 0xffffu) | (A.w << 16);  vl.y = (A.z >> 16) | (A.w & 0xffff0000u);
  vh.z = (B.x & 0xffffu) | (B.y << 16);  vl.z = (B.x >> 16) | (B.y & 0xffff0000u);
  vh.w = (B.z & 0xffffu) | (B.w << 16);  vl.w = (B.z >> 16) | (B.w & 0xffff0000u);
}

// ------- Kernel 0: x fp32 [b][c][hw] -> XTh/XTl bf16 hi/lo split, pixel-major [pix][c] -------
__global__ __launch_bounds__(256) void split_in(const float* __restrict__ x,
                                                u16* __restrict__ XTh,
                                                u16* __restrict__ XTl)
{
  __shared__ float tile[64 * 68];
  int t = threadIdx.x;
  int hw0 = blockIdx.x * 64, c0 = blockIdx.y * 64, b = blockIdx.z;
  {
    int cl = t >> 2, seg = (t & 3) * 16;
    const float* src = x + (b * 256 + c0 + cl) * 4096 + hw0 + seg;
    float4 v0 = ((const float4*)src)[0];
    float4 v1 = ((const float4*)src)[1];
    float4 v2 = ((const float4*)src)[2];
    float4 v3 = ((const float4*)src)[3];
    float* d = tile + cl * 68 + seg;
    ((float4*)d)[0] = v0; ((float4*)d)[1] = v1;
    ((float4*)d)[2] = v2; ((float4*)d)[3] = v3;
  }
  __syncthreads();
  {
    int hwl = t >> 2, cs = (t & 3) * 16;
    u32 ph[8], pl[8];
    #pragma unroll
    for (int e = 0; e < 8; ++e) {
      float v0 = tile[(cs + 2 * e) * 68 + hwl];
      float v1 = tile[(cs + 2 * e + 1) * 68 + hwl];
      u16 h0 = f2bf(v0), h1 = f2bf(v1);
      u16 l0 = f2bf(v0 - bf2f(h0)), l1 = f2bf(v1 - bf2f(h1));
      ph[e] = (u32)h0 | ((u32)h1 << 16);
      pl[e] = (u32)l0 | ((u32)l1 << 16);
    }
    int off = (b * 4096 + hw0 + hwl) * 256 + c0 + cs;
    *(uint4*)(XTh + off)     = make_uint4(ph[0], ph[1], ph[2], ph[3]);
    *(uint4*)(XTh + off + 8) = make_uint4(ph[4], ph[5], ph[6], ph[7]);
    *(uint4*)(XTl + off)     = make_uint4(pl[0], pl[1], pl[2], pl[3]);
    *(uint4*)(XTl + off + 8) = make_uint4(pl[4], pl[5], pl[6], pl[7]);
  }
}

// ------- Kernel 0b: w1|w2|w3 fp32 [o][c] -> Wh/Wl bf16 hi/lo -------
__global__ __launch_bounds__(256) void wsplit(const float* __restrict__ w1,
                                              const float* __restrict__ w2,
                                              const float* __restrict__ w3,
                                              u16* __restrict__ Wh,
                                              u16* __restrict__ Wl)
{
  int i = (blockIdx.x * 256 + threadIdx.x) * 4;
  int z = i >> 16, off = i & 65535;
  const float* w = (z == 0) ? w1 : ((z == 1) ? w2 : w3);
  float4 v = *(const float4*)(w + off);
  u16 h0 = f2bf(v.x), h1 = f2bf(v.y), h2 = f2bf(v.z), h3 = f2bf(v.w);
  u16 l0 = f2bf(v.x - bf2f(h0)), l1 = f2bf(v.y - bf2f(h1));
  u16 l2 = f2bf(v.z - bf2f(h2)), l3 = f2bf(v.w - bf2f(h3));
  uint2 hv; hv.x = (u32)h0 | ((u32)h1 << 16); hv.y = (u32)h2 | ((u32)h3 << 16);
  uint2 lv; lv.x = (u32)l0 | ((u32)l1 << 16); lv.y = (u32)l2 | ((u32)l3 << 16);
  *(uint2*)(Wh + i) = hv;
  *(uint2*)(Wl + i) = lv;
}

// ------- Kernel 1: q/k via 3-pass split-bf16 MFMA -> INTERLEAVED u32 (h|l<<16)
//         pixel-major [pix][c]; v via 1-pass -> bf16 c-major [o][pix]. grid (128, 2, 3).
//         (R4 structure: global_load_lds staging, source-chunk XOR involution.)
//         Epilogue z<2: 64 u32 stores/thread (was 128 u16) with 64B quarter-wave segments. -------
__global__ __launch_bounds__(256) void qkv_gemm(const u16* __restrict__ XTh,
                                                const u16* __restrict__ XTl,
                                                const u16* __restrict__ Wh,
                                                const u16* __restrict__ Wl,
                                                u32* __restrict__ qI,
                                                u32* __restrict__ kI,
                                                u16* __restrict__ vo)
{
  __shared__ u16 lAh[128 * 32];
  __shared__ u16 lBh[128 * 32];
  __shared__ u16 lAl[128 * 32];
  __shared__ u16 lBl[128 * 32];
  const int z = blockIdx.z;
  const int t = threadIdx.x;
  const int lane = t & 63, wv = t >> 6;
  const int ln15 = lane & 15, q = lane >> 4;
  const int pix0 = blockIdx.x * 128;
  const int o0 = blockIdx.y * 128;
  const int pw = (wv >> 1) * 64, ow = (wv & 1) * 64;
  f32x4 acc[4][4];
  #pragma unroll
  for (int i = 0; i < 4; ++i)
    #pragma unroll
    for (int j = 0; j < 4; ++j)
      acc[i][j] = (f32x4){0.f, 0.f, 0.f, 0.f};

  const int Lr = lane >> 2;
  const int cswz = (lane & 3) ^ ((lane >> 3) & 3);
  const int r0 = wv * 32 + Lr;          // slice 0 row
  const int r1 = wv * 32 + 16 + Lr;     // slice 1 row
  const int gA0 = (pix0 + r0) * 256 + cswz * 8;
  const int gA1 = (pix0 + r1) * 256 + cswz * 8;
  const int gB0 = z * 65536 + (o0 + r0) * 256 + cswz * 8;
  const int gB1 = z * 65536 + (o0 + r1) * 256 + cswz * 8;
  const int s0 = wv * 1024;             // wave-uniform LDS slice bases (u16 units)
  const int s1 = wv * 1024 + 512;
  const int qsw = (q ^ ((ln15 >> 1) & 3)) * 8;   // read-side chunk swizzle (u16 units)

  for (int kc = 0; kc < 256; kc += 32) {
    __syncthreads();                    // previous K-step done reading LDS
    __builtin_amdgcn_global_load_lds((const u32*)(XTh + gA0 + kc), (u32*)(lAh + s0), 16, 0, 0);
    __builtin_amdgcn_global_load_lds((const u32*)(XTh + gA1 + kc), (u32*)(lAh + s1), 16, 0, 0);
    __builtin_amdgcn_global_load_lds((const u32*)(Wh  + gB0 + kc), (u32*)(lBh + s0), 16, 0, 0);
    __builtin_amdgcn_global_load_lds((const u32*)(Wh  + gB1 + kc), (u32*)(lBh + s1), 16, 0, 0);
    if (z < 2) {
      __builtin_amdgcn_global_load_lds((const u32*)(XTl + gA0 + kc), (u32*)(lAl + s0), 16, 0, 0);
      __builtin_amdgcn_global_load_lds((const u32*)(XTl + gA1 + kc), (u32*)(lAl + s1), 16, 0, 0);
      __builtin_amdgcn_global_load_lds((const u32*)(Wl  + gB0 + kc), (u32*)(lBl + s0), 16, 0, 0);
      __builtin_amdgcn_global_load_lds((const u32*)(Wl  + gB1 + kc), (u32*)(lBl + s1), 16, 0, 0);
    }
    __syncthreads();                    // vmcnt drained at barrier -> tiles visible
    short8 afh[4], bfh[4];
    #pragma unroll
    for (int i = 0; i < 4; ++i)
      afh[i] = *(const short8*)(lAh + (pw + i * 16 + ln15) * 32 + qsw);
    #pragma unroll
    for (int j = 0; j < 4; ++j)
      bfh[j] = *(const short8*)(lBh + (ow + j * 16 + ln15) * 32 + qsw);
    #pragma unroll
    for (int i = 0; i < 4; ++i)
      #pragma unroll
      for (int j = 0; j < 4; ++j)
        acc[i][j] = __builtin_amdgcn_mfma_f32_16x16x32_bf16(afh[i], bfh[j], acc[i][j], 0, 0, 0);
    if (z < 2) {
      short8 afl[4], bfl[4];
      #pragma unroll
      for (int i = 0; i < 4; ++i)
        afl[i] = *(const short8*)(lAl + (pw + i * 16 + ln15) * 32 + qsw);
      #pragma unroll
      for (int j = 0; j < 4; ++j)
        bfl[j] = *(const short8*)(lBl + (ow + j * 16 + ln15) * 32 + qsw);
      #pragma unroll
      for (int i = 0; i < 4; ++i)
        #pragma unroll
        for (int j = 0; j < 4; ++j) {
          acc[i][j] = __builtin_amdgcn_mfma_f32_16x16x32_bf16(afh[i], bfl[j], acc[i][j], 0, 0, 0);
          acc[i][j] = __builtin_amdgcn_mfma_f32_16x16x32_bf16(afl[i], bfh[j], acc[i][j], 0, 0, 0);
        }
    }
  }

  // D: m(pixel) = pw + i*16 + q*4 + r, n(o) = ow + j*16 + ln15
  if (z == 2) {
    // v: c-major [o][pix]; 4 acc regs = 4 consecutive pixels -> packed uint2 store
    #pragma unroll
    for (int i = 0; i < 4; ++i) {
      int pixb = pix0 + pw + i * 16 + q * 4;
      #pragma unroll
      for (int j = 0; j < 4; ++j) {
        int o = o0 + ow + j * 16 + ln15;
        u32 p0 = (u32)f2bf(acc[i][j][0]) | ((u32)f2bf(acc[i][j][1]) << 16);
        u32 p1 = (u32)f2bf(acc[i][j][2]) | ((u32)f2bf(acc[i][j][3]) << 16);
        uint2 pvv; pvv.x = p0; pvv.y = p1;
        *(uint2*)(vo + o * 16384 + pixb) = pvv;
      }
    }
  } else {
    u32* dst = (z == 0) ? qI : kI;
    #pragma unroll
    for (int i = 0; i < 4; ++i) {
      #pragma unroll
      for (int r = 0; r < 4; ++r) {
        int pix = pix0 + pw + i * 16 + q * 4 + r;
        int ob = o0 + ow + ln15;
        #pragma unroll
        for (int j = 0; j < 4; ++j) {
          float vv = acc[i][j][r];
          u16 hh = f2bf(vv);
          u16 ll = f2bf(vv - bf2f(hh));
          dst[pix * 256 + ob + j * 16] = (u32)hh | ((u32)ll << 16);
        }
      }
    }
  }
}

// ------- Kernel 2: banded-MFMA local attention. Block = quarter row (16 q-px).
// q/k arrive INTERLEAVED (u32 = h|l<<16, pixel-major [pix][c]); staging unpacks via
// shift/mask (v_perm-fusable) before ds_write — LDS layouts and fragment reads are
// byte-identical to R8. v c-major, phase 2 fragment = one ds_read_b128. -------
__global__ __launch_bounds__(256, 4) void attn(const u32* __restrict__ qI,
                                               const u32* __restrict__ kI,
                                               const u16* __restrict__ vo,
                                               float* __restrict__ out)
{
  __shared__ u16 kst[12288];             // 24576 B: k hi @0, k lo @+12288B; q @0/+8192B; v tile @0 (16 KB)
  __shared__ float lg2[2][16][57];       // 7296 B
  __shared__ u16 pb[7][16][40];          // 8960 B   (total 40832 <= 40960 -> 4 blocks/CU)

  const int t = threadIdx.x;
  const int lane = t & 63, wv = t >> 6;
  const int l15 = lane & 15, q4 = lane >> 4;
  const int bid = ((int)blockIdx.x & 7) * 128 + ((int)blockIdx.x >> 3);  // XCD-bijective
  const int quarter = bid & 3;
  const int row = bid >> 2;               // b*64 + h
  const int b = row >> 6, h = row & 63;
  const int wbase = quarter * 16;
  char* sk = (char*)kst;

  for (int i = t; i < 2 * 16 * 57; i += 256) ((float*)lg2)[i] = 0.f;
  for (int i = t; i < 2240; i += 256) ((u32*)pb)[i] = 0u;

  // ---------- q stage (coalesced; unpack h/l then swzb write) ----------
  #pragma unroll
  for (int it = 0; it < 2; ++it) {
    const int s = t + it * 256;                 // 0..511
    const int px = s >> 5, co = s & 31;
    const u32* src = qI + (row * 64 + wbase + px) * 256 + co * 8;
    const uint4 A = ((const uint4*)src)[0];
    const uint4 B = ((const uint4*)src)[1];
    uint4 vh, vl; unpk(A, B, vh, vl);
    const int off = swzb(px, co);
    *(uint4*)(sk + off) = vh;
    *(uint4*)(sk + 8192 + off) = vl;
  }

  const int ch = wv >> 1, win = wv & 1;          // wave -> (c-half, n-window)
  uint4 pA[3], pB[3];                            // raw interleaved k prefetch
  // k prefetch for dh=0 (flies during barrier + q-frag reads)
  {
    const int rdh0 = h - 3;
    const int rdhc = rdh0 < 0 ? 0 : rdh0;
    const int rp = (b * 64 + rdhc) * 64;
    #pragma unroll
    for (int it = 0; it < 3; ++it) {
      const int s = t + it * 256;
      const int px = s >> 5, co = s & 31;
      const int w = wbase - 4 + px;
      const int wc = w < 0 ? 0 : (w > 63 ? 63 : w);
      const u32* src = kI + (rp + wc) * 256 + co * 8;
      uint4 A = ((const uint4*)src)[0];
      uint4 B = ((const uint4*)src)[1];
      const bool zz = (w < 0) | (w > 63);
      pA[it].x = zz ? 0u : A.x; pA[it].y = zz ? 0u : A.y; pA[it].z = zz ? 0u : A.z; pA[it].w = zz ? 0u : A.w;
      pB[it].x = zz ? 0u : B.x; pB[it].y = zz ? 0u : B.y; pB[it].z = zz ? 0u : B.z; pB[it].w = zz ? 0u : B.w;
    }
  }
  __syncthreads();

  // q fragments from LDS
  short8 qfh[4], qfl[4];
  #pragma unroll
  for (int u = 0; u < 4; ++u) {
    const int co = (ch * 4 + u) * 4 + q4;
    const int off = swzb(l15, co);
    qfh[u] = *(const short8*)(sk + off);
    qfl[u] = *(const short8*)(sk + 8192 + off);
  }

  // ---------- phase 1: logits ----------
  const int tidx = win ? (l15 + 12 > 23 ? 23 : l15 + 12) : (l15 - 4 < 0 ? 0 : l15 - 4);
  #pragma unroll 1
  for (int dh = 0; dh < 7; ++dh) {
    __syncthreads();                      // previous compute done reading kst
    #pragma unroll
    for (int it = 0; it < 3; ++it) {      // WRITEK (unpack + swzb write)
      const int s = t + it * 256;
      const int px = s >> 5, co = s & 31;
      uint4 vh, vl; unpk(pA[it], pB[it], vh, vl);
      const int off = swzb(px, co);
      *(uint4*)(sk + off) = vh;
      *(uint4*)(sk + 12288 + off) = vl;
    }
    if (dh < 6) {                         // LOADK(dh+1): flies during compute
      const int rdh1 = h + dh - 2;
      const int rdhc = rdh1 < 0 ? 0 : (rdh1 > 63 ? 63 : rdh1);
      const int rp = (b * 64 + rdhc) * 64;
      #pragma unroll
      for (int it = 0; it < 3; ++it) {
        const int s = t + it * 256;
        const int px = s >> 5, co = s & 31;
        const int w = wbase - 4 + px;
        const int wc = w < 0 ? 0 : (w > 63 ? 63 : w);
        const u32* src = kI + (rp + wc) * 256 + co * 8;
        uint4 A = ((const uint4*)src)[0];
        uint4 B = ((const uint4*)src)[1];
        const bool zz = (w < 0) | (w > 63);
        pA[it].x = zz ? 0u : A.x; pA[it].y = zz ? 0u : A.y; pA[it].z = zz ? 0u : A.z; pA[it].w = zz ? 0u : A.w;
        pB[it].x = zz ? 0u : B.x; pB[it].y = zz ? 0u : B.y; pB[it].z = zz ? 0u : B.z; pB[it].w = zz ? 0u : B.w;
      }
    }
    __syncthreads();                      // staged tile visible
    const int rdh = h + dh - 3;
    const bool rok = (rdh >= 0) && (rdh < 64);
    f32x4 a0 = {0.f, 0.f, 0.f, 0.f};
    f32x4 a1 = {0.f, 0.f, 0.f, 0.f};     // split chains for MFMA ILP
    #pragma unroll
    for (int u = 0; u < 4; ++u) {
      const int co = (ch * 4 + u) * 4 + q4;
      const int off = swzb(tidx, co);
      const short8 bh_ = *(const short8*)(sk + off);
      const short8 bl_ = *(const short8*)(sk + 12288 + off);
      a0 = __builtin_amdgcn_mfma_f32_16x16x32_bf16(qfh[u], bh_, a0, 0, 0, 0);
      a1 = __builtin_amdgcn_mfma_f32_16x16x32_bf16(qfh[u], bl_, a1, 0, 0, 0);
      a0 = __builtin_amdgcn_mfma_f32_16x16x32_bf16(qfl[u], bh_, a0, 0, 0, 0);
    }
    // scatter band entries: D col n=l15, row m=q4*4+r; dw = n_w - m_w + 3
    #pragma unroll
    for (int r = 0; r < 4; ++r) {
      const int mloc = q4 * 4 + r;
      const int dw = l15 - mloc - 5 + win * 16;
      if (rok && dw >= 0 && dw < 7) lg2[ch][mloc][dh * 7 + dw] = a0[r] + a1[r];
    }
  }

  // v prefetch for dh=0 (c-major vo[o*16384+pix]; flies during softmax)
  uint4 pv[4];
  {
    const int rdh0 = h - 3;
    const bool rok2 = rdh0 >= 0;
    const int rdhc = rdh0 < 0 ? 0 : rdh0;
    const int rp = (b * 64 + rdhc) * 64;
    #pragma unroll
    for (int it = 0; it < 4; ++it) {
      const int s = t + it * 256;                // 0..1023
      const int c = s >> 2, po = s & 3;          // channel, px-octet
      const int w0 = wbase - 8 + po * 8;
      const int wc = w0 < 0 ? 0 : (w0 > 56 ? 56 : w0);
      const int g = c * 16384 + rp + wc;
      uint4 vv = *(const uint4*)(vo + g);
      const bool zz = (!rok2) | (w0 < 0) | (w0 > 56);
      pv[it].x = zz ? 0u : vv.x; pv[it].y = zz ? 0u : vv.y; pv[it].z = zz ? 0u : vv.z; pv[it].w = zz ? 0u : vv.w;
    }
  }
  __syncthreads();

  // ---------- softmax: 16 lanes per pixel ----------
  {
    const int px = t >> 4, sub = t & 15;
    float mx = -3.0e38f;
    for (int i = sub; i < 49; i += 16)
      mx = fmaxf(mx, lg2[0][px][i] + lg2[1][px][i]);
    mx = fmaxf(mx, __shfl_xor(mx, 1));
    mx = fmaxf(mx, __shfl_xor(mx, 2));
    mx = fmaxf(mx, __shfl_xor(mx, 4));
    mx = fmaxf(mx, __shfl_xor(mx, 8));
    float s = 0.f;
    for (int i = sub; i < 49; i += 16) {
      float v = __expf(lg2[0][px][i] + lg2[1][px][i] - mx);
      lg2[0][px][i] = v;                  // stash exp (same-lane RAW only)
      s += v;
    }
    s += __shfl_xor(s, 1);
    s += __shfl_xor(s, 2);
    s += __shfl_xor(s, 4);
    s += __shfl_xor(s, 8);
    const float inv = 1.f / s;
    for (int i = sub; i < 49; i += 16) {
      const int dh7 = i / 7, dw7 = i - dh7 * 7;
      pb[dh7][px][px + 5 + dw7] = f2bf(lg2[0][px][i] * inv);
    }
  }

  // ---------- phase 2: out[c][m'] = sum_n' v[c][n'] * P[m'][n'] ----------
  // LDS v tile: byte off = c*64 + ((po ^ ((c&3)^((c>>2)&3)))*16) + (px&7)*2
  f32x4 acc[4];
  #pragma unroll
  for (int i = 0; i < 4; ++i) acc[i] = (f32x4){0.f, 0.f, 0.f, 0.f};
  #pragma unroll 1
  for (int dh = 0; dh < 7; ++dh) {
    __syncthreads();                      // kst free (phase1 / prev iter done)
    #pragma unroll
    for (int it = 0; it < 4; ++it) {      // WRITEV (swizzled c-major tile)
      const int s = t + it * 256;
      const int c = s >> 2, po = s & 3;
      const int sc = (c & 3) ^ ((c >> 2) & 3);
      *(uint4*)(sk + c * 64 + ((po ^ sc) * 16)) = pv[it];
    }
    if (dh < 6) {                         // LOADV(dh+1)
      const int rdh1 = h + dh - 2;
      const bool rok2 = (rdh1 >= 0) && (rdh1 < 64);
      const int rdhc = rdh1 < 0 ? 0 : (rdh1 > 63 ? 63 : rdh1);
      const int rp = (b * 64 + rdhc) * 64;
      #pragma unroll
      for (int it = 0; it < 4; ++it) {
        const int s = t + it * 256;
        const int c = s >> 2, po = s & 3;
        const int w0 = wbase - 8 + po * 8;
        const int wc = w0 < 0 ? 0 : (w0 > 56 ? 56 : w0);
        const int g = c * 16384 + rp + wc;
        uint4 vv = *(const uint4*)(vo + g);
        const bool zz = (!rok2) | (w0 < 0) | (w0 > 56);
        pv[it].x = zz ? 0u : vv.x; pv[it].y = zz ? 0u : vv.y; pv[it].z = zz ? 0u : vv.z; pv[it].w = zz ? 0u : vv.w;
      }
    }
    __syncthreads();                      // tile visible
    #pragma unroll
    for (int i = 0; i < 4; ++i) {
      const int c = wv * 64 + i * 16 + l15;      // A: m = channel, k-octet = q4
      const int sc = (c & 3) ^ ((c >> 2) & 3);
      const short8 af = *(const short8*)(sk + c * 64 + ((q4 ^ sc) * 16));
      const short8 bf_ = *(const short8*)(&pb[dh][l15][q4 * 8]);
      acc[i] = __builtin_amdgcn_mfma_f32_16x16x32_bf16(af, bf_, acc[i], 0, 0, 0);
    }
  }
  #pragma unroll
  for (int i = 0; i < 4; ++i) {
    const int ct = wv * 4 + i;
    // D: row m = channel q4*4+r, col n = pixel l15 -> native [b][c][h][w]
    #pragma unroll
    for (int r = 0; r < 4; ++r)
      out[(b * 256 + ct * 16 + q4 * 4 + r) * 4096 + h * 64 + wbase + l15] = acc[i][r];
  }
}

extern "C" void kernel_launch(void* const* d_in, const int* in_sizes, int n_in,
                              void* d_out, int out_size, void* d_ws, size_t ws_size,
                              hipStream_t stream)
{
  const float* x  = (const float*)d_in[0];
  const float* w1 = (const float*)d_in[1];
  const float* w2 = (const float*)d_in[2];
  const float* w3 = (const float*)d_in[3];
  float* out = (float*)d_out;

  // x hi/lo bf16 split lives in d_out (16 MB); consumed by qkv_gemm, then d_out is
  // fully rewritten by attn phase 2 (stream-ordered).
  u16* XTh = (u16*)d_out;
  u16* XTl = XTh + 4194304;

  char* ws = (char*)d_ws;
  u32* qI = (u32*)ws;                      // 16 MB interleaved q (h|l<<16), pixel-major [pix][c]
  u32* kI = (u32*)(ws + (16u << 20));      // 16 MB interleaved k
  u16* vo = (u16*)(ws + (32u << 20));      // 8 MB bf16 v, c-major [o][pix]
  u16* Wh = (u16*)(ws + (40u << 20));      // 384 KB
  u16* Wl = Wh + 196608;                   // 384 KB

  split_in<<<dim3(64, 4, 4), 256, 0, stream>>>(x, XTh, XTl);
  wsplit<<<192, 256, 0, stream>>>(w1, w2, w3, Wh, Wl);
  qkv_gemm<<<dim3(128, 2, 3), 256, 0, stream>>>(XTh, XTl, Wh, Wl, qI, kI, vo);
  attn<<<dim3(1024), 256, 0, stream>>>(qI, kI, vo, out);
}

// Round 10
// 128.170 us; speedup vs baseline: 1.0155x; 1.0155x over previous
//
#include <hip/hip_runtime.h>

typedef unsigned short u16;
typedef unsigned int u32;
typedef __attribute__((ext_vector_type(8))) short short8;
typedef __attribute__((ext_vector_type(4))) float f32x4;

__device__ __forceinline__ float bf2f(u16 h){ return __builtin_bit_cast(float, ((u32)h) << 16); }
__device__ __forceinline__ u16 f2bf(float f){
  u32 u = __builtin_bit_cast(u32, f);
  u32 r = u + 0x7fffu + ((u >> 16) & 1u);
  return (u16)(r >> 16);
}
// byte offset of channel-octet `co` of tile-pixel `px` in a swizzled [px][256ch] bf16 LDS tile
__device__ __forceinline__ int swzb(int px, int co){
  return px * 512 + ((co * 16) ^ ((((px & 7) ^ ((px >> 3) * 3)) & 7) << 4));
}
// unpack 8 interleaved (h|l<<16) channel words (2 uint4) -> vh (8 bf16 hi), vl (8 bf16 lo)
__device__ __forceinline__ void unpk(const uint4 A, const uint4 B, uint4& vh, uint4& vl){
  vh.x = (A.x & 0xffffu) | (A.y << 16);  vl.x = (A.x >> 16) | (A.y & 0xffff0000u);
  vh.y = (A.z & 0xffffu) | (A.w << 16);  vl.y = (A.z >> 16) | (A.w & 0xffff0000u);
  vh.z = (B.x & 0xffffu) | (B.y << 16);  vl.z = (B.x >> 16) | (B.y & 0xffff0000u);
  vh.w = (B.z & 0xffffu) | (B.w << 16);  vl.w = (B.z >> 16) | (B.w & 0xffff0000u);
}

// ------- Kernel 0b: w1|w2|w3 fp32 [o][c] -> Wh/Wl bf16 hi/lo -------
__global__ __launch_bounds__(256) void wsplit(const float* __restrict__ w1,
                                              const float* __restrict__ w2,
                                              const float* __restrict__ w3,
                                              u16* __restrict__ Wh,
                                              u16* __restrict__ Wl)
{
  int i = (blockIdx.x * 256 + threadIdx.x) * 4;
  int z = i >> 16, off = i & 65535;
  const float* w = (z == 0) ? w1 : ((z == 1) ? w2 : w3);
  float4 v = *(const float4*)(w + off);
  u16 h0 = f2bf(v.x), h1 = f2bf(v.y), h2 = f2bf(v.z), h3 = f2bf(v.w);
  u16 l0 = f2bf(v.x - bf2f(h0)), l1 = f2bf(v.y - bf2f(h1));
  u16 l2 = f2bf(v.z - bf2f(h2)), l3 = f2bf(v.w - bf2f(h3));
  uint2 hv; hv.x = (u32)h0 | ((u32)h1 << 16); hv.y = (u32)h2 | ((u32)h3 << 16);
  uint2 lv; lv.x = (u32)l0 | ((u32)l1 << 16); lv.y = (u32)l2 | ((u32)l3 << 16);
  *(uint2*)(Wh + i) = hv;
  *(uint2*)(Wl + i) = lv;
}

// ------- Kernel 1: fused split+qkv. A staged DIRECTLY from fp32 x (register transpose:
// channel-pair x pixel-quad -> packed u32 writes into stride-34 pixel-major A-tile;
// f2bf hi/lo split identical to old split_in -> bit-identical numerics). A-regs for kc+1
// prefetched during compute of kc (T14). B via global_load_lds as before (R4 pattern).
// q/k out: interleaved u32 (h|l<<16) pixel-major; v: bf16 c-major [o][pix]. grid (128,2,3). -------
#define ASTR 34   // A-tile row stride in u16 (odd-word 17 -> bank spread, no XOR needed)
__global__ __launch_bounds__(256) void qkv_gemm(const float* __restrict__ x,
                                                const u16* __restrict__ Wh,
                                                const u16* __restrict__ Wl,
                                                u32* __restrict__ qI,
                                                u32* __restrict__ kI,
                                                u16* __restrict__ vo)
{
  __shared__ u16 lAh[128 * ASTR];
  __shared__ u16 lAl[128 * ASTR];
  __shared__ u16 lBh[128 * 32];
  __shared__ u16 lBl[128 * 32];
  const int z = blockIdx.z;
  const int t = threadIdx.x;
  const int lane = t & 63, wv = t >> 6;
  const int ln15 = lane & 15, q = lane >> 4;
  const int pix0 = blockIdx.x * 128;
  const int o0 = blockIdx.y * 128;
  const int pw = (wv >> 1) * 64, ow = (wv & 1) * 64;
  const int b = pix0 >> 12, hw0 = pix0 & 4095;
  f32x4 acc[4][4];
  #pragma unroll
  for (int i = 0; i < 4; ++i)
    #pragma unroll
    for (int j = 0; j < 4; ++j)
      acc[i][j] = (f32x4){0.f, 0.f, 0.f, 0.f};

  // ---- B staging geometry (R4-proven) ----
  const int Lr = lane >> 2;
  const int cswz = (lane & 3) ^ ((lane >> 3) & 3);
  const int r0 = wv * 32 + Lr;
  const int r1 = wv * 32 + 16 + Lr;
  const int gB0 = z * 65536 + (o0 + r0) * 256 + cswz * 8;
  const int gB1 = z * 65536 + (o0 + r1) * 256 + cswz * 8;
  const int s0 = wv * 1024;
  const int s1 = wv * 1024 + 512;
  const int qsw = (q ^ ((ln15 >> 1) & 3)) * 8;   // B read-side chunk swizzle (u16)

  // ---- A staging geometry: thread-iter handles channel-pair cpair, pixel-quad pxq ----
  const int idx0 = t, idx1 = t + 256;            // 512 (cpair,pxq) slots: 16 cpair x 32 pxq
  const int cp0 = idx0 >> 5, pq0 = idx0 & 31;
  const int cp1 = idx1 >> 5, pq1 = idx1 & 31;
  const float* xb = x + (b * 256) * 4096 + hw0;  // x[(b*256+c)*4096 + hw]
  u32* lAh32 = (u32*)lAh;
  u32* lAl32 = (u32*)lAl;

  float4 a0A, a0B, a1A, a1B;   // prefetched A quads: (iter0: ch 2cp0,2cp0+1) (iter1: ...)
  {
    a0A = *(const float4*)(xb + (2 * cp0) * 4096 + pq0 * 4);
    a0B = *(const float4*)(xb + (2 * cp0 + 1) * 4096 + pq0 * 4);
    a1A = *(const float4*)(xb + (2 * cp1) * 4096 + pq1 * 4);
    a1B = *(const float4*)(xb + (2 * cp1 + 1) * 4096 + pq1 * 4);
  }

  for (int kc8 = 0; kc8 < 8; ++kc8) {
    __syncthreads();                    // previous K-step done reading LDS
    // B stage (fire-and-forget; drains at next barrier)
    __builtin_amdgcn_global_load_lds((const u32*)(Wh + gB0 + kc8 * 32), (u32*)(lBh + s0), 16, 0, 0);
    __builtin_amdgcn_global_load_lds((const u32*)(Wh + gB1 + kc8 * 32), (u32*)(lBh + s1), 16, 0, 0);
    if (z < 2) {
      __builtin_amdgcn_global_load_lds((const u32*)(Wl + gB0 + kc8 * 32), (u32*)(lBl + s0), 16, 0, 0);
      __builtin_amdgcn_global_load_lds((const u32*)(Wl + gB1 + kc8 * 32), (u32*)(lBl + s1), 16, 0, 0);
    }
    // A stage: convert prefetched fp32 quads -> hi/lo bf16, packed u32 writes
    {
      const float* pa[4] = {&a0A.x, &a0B.x, &a1A.x, &a1B.x};
      const int cps[2] = {cp0, cp1};
      const int pqs[2] = {pq0, pq1};
      #pragma unroll
      for (int it = 0; it < 2; ++it) {
        const float* vA = pa[it * 2];
        const float* vB = pa[it * 2 + 1];
        #pragma unroll
        for (int j = 0; j < 4; ++j) {
          const u16 hA = f2bf(vA[j]), hB = f2bf(vB[j]);
          const int w = (pqs[it] * 4 + j) * 17 + cps[it];
          lAh32[w] = (u32)hA | ((u32)hB << 16);
          if (z < 2) {
            const u16 lA_ = f2bf(vA[j] - bf2f(hA));
            const u16 lB_ = f2bf(vB[j] - bf2f(hB));
            lAl32[w] = (u32)lA_ | ((u32)lB_ << 16);
          }
        }
      }
    }
    if (kc8 < 7) {                      // T14: prefetch A quads for next K-step (fly under compute)
      const float* xn = xb + (kc8 + 1) * 32 * 4096;
      a0A = *(const float4*)(xn + (2 * cp0) * 4096 + pq0 * 4);
      a0B = *(const float4*)(xn + (2 * cp0 + 1) * 4096 + pq0 * 4);
      a1A = *(const float4*)(xn + (2 * cp1) * 4096 + pq1 * 4);
      a1B = *(const float4*)(xn + (2 * cp1 + 1) * 4096 + pq1 * 4);
    }
    __syncthreads();                    // tiles visible (gload_lds drained, ds_writes done)
    short8 afh[4], bfh[4];
    #pragma unroll
    for (int i = 0; i < 4; ++i)
      afh[i] = *(const short8*)(lAh + (pw + i * 16 + ln15) * ASTR + q * 8);
    #pragma unroll
    for (int j = 0; j < 4; ++j)
      bfh[j] = *(const short8*)(lBh + (ow + j * 16 + ln15) * 32 + qsw);
    #pragma unroll
    for (int i = 0; i < 4; ++i)
      #pragma unroll
      for (int j = 0; j < 4; ++j)
        acc[i][j] = __builtin_amdgcn_mfma_f32_16x16x32_bf16(afh[i], bfh[j], acc[i][j], 0, 0, 0);
    if (z < 2) {
      short8 afl[4], bfl[4];
      #pragma unroll
      for (int i = 0; i < 4; ++i)
        afl[i] = *(const short8*)(lAl + (pw + i * 16 + ln15) * ASTR + q * 8);
      #pragma unroll
      for (int j = 0; j < 4; ++j)
        bfl[j] = *(const short8*)(lBl + (ow + j * 16 + ln15) * 32 + qsw);
      #pragma unroll
      for (int i = 0; i < 4; ++i)
        #pragma unroll
        for (int j = 0; j < 4; ++j) {
          acc[i][j] = __builtin_amdgcn_mfma_f32_16x16x32_bf16(afh[i], bfl[j], acc[i][j], 0, 0, 0);
          acc[i][j] = __builtin_amdgcn_mfma_f32_16x16x32_bf16(afl[i], bfh[j], acc[i][j], 0, 0, 0);
        }
    }
  }

  // D: m(pixel) = pw + i*16 + q*4 + r, n(o) = ow + j*16 + ln15
  if (z == 2) {
    // v: c-major [o][pix]; 4 acc regs = 4 consecutive pixels -> packed uint2 store
    #pragma unroll
    for (int i = 0; i < 4; ++i) {
      int pixb = pix0 + pw + i * 16 + q * 4;
      #pragma unroll
      for (int j = 0; j < 4; ++j) {
        int o = o0 + ow + j * 16 + ln15;
        u32 p0 = (u32)f2bf(acc[i][j][0]) | ((u32)f2bf(acc[i][j][1]) << 16);
        u32 p1 = (u32)f2bf(acc[i][j][2]) | ((u32)f2bf(acc[i][j][3]) << 16);
        uint2 pvv; pvv.x = p0; pvv.y = p1;
        *(uint2*)(vo + o * 16384 + pixb) = pvv;
      }
    }
  } else {
    u32* dst = (z == 0) ? qI : kI;
    #pragma unroll
    for (int i = 0; i < 4; ++i) {
      #pragma unroll
      for (int r = 0; r < 4; ++r) {
        int pix = pix0 + pw + i * 16 + q * 4 + r;
        int ob = o0 + ow + ln15;
        #pragma unroll
        for (int j = 0; j < 4; ++j) {
          float vv = acc[i][j][r];
          u16 hh = f2bf(vv);
          u16 ll = f2bf(vv - bf2f(hh));
          dst[pix * 256 + ob + j * 16] = (u32)hh | ((u32)ll << 16);
        }
      }
    }
  }
}

// ------- Kernel 2: banded-MFMA local attention (unchanged from R9). -------
__global__ __launch_bounds__(256, 4) void attn(const u32* __restrict__ qI,
                                               const u32* __restrict__ kI,
                                               const u16* __restrict__ vo,
                                               float* __restrict__ out)
{
  __shared__ u16 kst[12288];             // 24576 B: k hi @0, k lo @+12288B; q @0/+8192B; v tile @0 (16 KB)
  __shared__ float lg2[2][16][57];       // 7296 B
  __shared__ u16 pb[7][16][40];          // 8960 B   (total 40832 <= 40960 -> 4 blocks/CU)

  const int t = threadIdx.x;
  const int lane = t & 63, wv = t >> 6;
  const int l15 = lane & 15, q4 = lane >> 4;
  const int bid = ((int)blockIdx.x & 7) * 128 + ((int)blockIdx.x >> 3);  // XCD-bijective
  const int quarter = bid & 3;
  const int row = bid >> 2;               // b*64 + h
  const int b = row >> 6, h = row & 63;
  const int wbase = quarter * 16;
  char* sk = (char*)kst;

  for (int i = t; i < 2 * 16 * 57; i += 256) ((float*)lg2)[i] = 0.f;
  for (int i = t; i < 2240; i += 256) ((u32*)pb)[i] = 0u;

  // ---------- q stage (coalesced; unpack h/l then swzb write) ----------
  #pragma unroll
  for (int it = 0; it < 2; ++it) {
    const int s = t + it * 256;                 // 0..511
    const int px = s >> 5, co = s & 31;
    const u32* src = qI + (row * 64 + wbase + px) * 256 + co * 8;
    const uint4 A = ((const uint4*)src)[0];
    const uint4 B = ((const uint4*)src)[1];
    uint4 vh, vl; unpk(A, B, vh, vl);
    const int off = swzb(px, co);
    *(uint4*)(sk + off) = vh;
    *(uint4*)(sk + 8192 + off) = vl;
  }

  const int ch = wv >> 1, win = wv & 1;          // wave -> (c-half, n-window)
  uint4 pA[3], pB[3];                            // raw interleaved k prefetch
  // k prefetch for dh=0 (flies during barrier + q-frag reads)
  {
    const int rdh0 = h - 3;
    const int rdhc = rdh0 < 0 ? 0 : rdh0;
    const int rp = (b * 64 + rdhc) * 64;
    #pragma unroll
    for (int it = 0; it < 3; ++it) {
      const int s = t + it * 256;
      const int px = s >> 5, co = s & 31;
      const int w = wbase - 4 + px;
      const int wc = w < 0 ? 0 : (w > 63 ? 63 : w);
      const u32* src = kI + (rp + wc) * 256 + co * 8;
      uint4 A = ((const uint4*)src)[0];
      uint4 B = ((const uint4*)src)[1];
      const bool zz = (w < 0) | (w > 63);
      pA[it].x = zz ? 0u : A.x; pA[it].y = zz ? 0u : A.y; pA[it].z = zz ? 0u : A.z; pA[it].w = zz ? 0u : A.w;
      pB[it].x = zz ? 0u : B.x; pB[it].y = zz ? 0u : B.y; pB[it].z = zz ? 0u : B.z; pB[it].w = zz ? 0u : B.w;
    }
  }
  __syncthreads();

  // q fragments from LDS
  short8 qfh[4], qfl[4];
  #pragma unroll
  for (int u = 0; u < 4; ++u) {
    const int co = (ch * 4 + u) * 4 + q4;
    const int off = swzb(l15, co);
    qfh[u] = *(const short8*)(sk + off);
    qfl[u] = *(const short8*)(sk + 8192 + off);
  }

  // ---------- phase 1: logits ----------
  const int tidx = win ? (l15 + 12 > 23 ? 23 : l15 + 12) : (l15 - 4 < 0 ? 0 : l15 - 4);
  #pragma unroll 1
  for (int dh = 0; dh < 7; ++dh) {
    __syncthreads();                      // previous compute done reading kst
    #pragma unroll
    for (int it = 0; it < 3; ++it) {      // WRITEK (unpack + swzb write)
      const int s = t + it * 256;
      const int px = s >> 5, co = s & 31;
      uint4 vh, vl; unpk(pA[it], pB[it], vh, vl);
      const int off = swzb(px, co);
      *(uint4*)(sk + off) = vh;
      *(uint4*)(sk + 12288 + off) = vl;
    }
    if (dh < 6) {                         // LOADK(dh+1): flies during compute
      const int rdh1 = h + dh - 2;
      const int rdhc = rdh1 < 0 ? 0 : (rdh1 > 63 ? 63 : rdh1);
      const int rp = (b * 64 + rdhc) * 64;
      #pragma unroll
      for (int it = 0; it < 3; ++it) {
        const int s = t + it * 256;
        const int px = s >> 5, co = s & 31;
        const int w = wbase - 4 + px;
        const int wc = w < 0 ? 0 : (w > 63 ? 63 : w);
        const u32* src = kI + (rp + wc) * 256 + co * 8;
        uint4 A = ((const uint4*)src)[0];
        uint4 B = ((const uint4*)src)[1];
        const bool zz = (w < 0) | (w > 63);
        pA[it].x = zz ? 0u : A.x; pA[it].y = zz ? 0u : A.y; pA[it].z = zz ? 0u : A.z; pA[it].w = zz ? 0u : A.w;
        pB[it].x = zz ? 0u : B.x; pB[it].y = zz ? 0u : B.y; pB[it].z = zz ? 0u : B.z; pB[it].w = zz ? 0u : B.w;
      }
    }
    __syncthreads();                      // staged tile visible
    const int rdh = h + dh - 3;
    const bool rok = (rdh >= 0) && (rdh < 64);
    f32x4 a0 = {0.f, 0.f, 0.f, 0.f};
    f32x4 a1 = {0.f, 0.f, 0.f, 0.f};     // split chains for MFMA ILP
    #pragma unroll
    for (int u = 0; u < 4; ++u) {
      const int co = (ch * 4 + u) * 4 + q4;
      const int off = swzb(tidx, co);
      const short8 bh_ = *(const short8*)(sk + off);
      const short8 bl_ = *(const short8*)(sk + 12288 + off);
      a0 = __builtin_amdgcn_mfma_f32_16x16x32_bf16(qfh[u], bh_, a0, 0, 0, 0);
      a1 = __builtin_amdgcn_mfma_f32_16x16x32_bf16(qfh[u], bl_, a1, 0, 0, 0);
      a0 = __builtin_amdgcn_mfma_f32_16x16x32_bf16(qfl[u], bh_, a0, 0, 0, 0);
    }
    // scatter band entries: D col n=l15, row m=q4*4+r; dw = n_w - m_w + 3
    #pragma unroll
    for (int r = 0; r < 4; ++r) {
      const int mloc = q4 * 4 + r;
      const int dw = l15 - mloc - 5 + win * 16;
      if (rok && dw >= 0 && dw < 7) lg2[ch][mloc][dh * 7 + dw] = a0[r] + a1[r];
    }
  }

  // v prefetch for dh=0 (c-major vo[o*16384+pix]; flies during softmax)
  uint4 pv[4];
  {
    const int rdh0 = h - 3;
    const bool rok2 = rdh0 >= 0;
    const int rdhc = rdh0 < 0 ? 0 : rdh0;
    const int rp = (b * 64 + rdhc) * 64;
    #pragma unroll
    for (int it = 0; it < 4; ++it) {
      const int s = t + it * 256;                // 0..1023
      const int c = s >> 2, po = s & 3;          // channel, px-octet
      const int w0 = wbase - 8 + po * 8;
      const int wc = w0 < 0 ? 0 : (w0 > 56 ? 56 : w0);
      const int g = c * 16384 + rp + wc;
      uint4 vv = *(const uint4*)(vo + g);
      const bool zz = (!rok2) | (w0 < 0) | (w0 > 56);
      pv[it].x = zz ? 0u : vv.x; pv[it].y = zz ? 0u : vv.y; pv[it].z = zz ? 0u : vv.z; pv[it].w = zz ? 0u : vv.w;
    }
  }
  __syncthreads();

  // ---------- softmax: 16 lanes per pixel ----------
  {
    const int px = t >> 4, sub = t & 15;
    float mx = -3.0e38f;
    for (int i = sub; i < 49; i += 16)
      mx = fmaxf(mx, lg2[0][px][i] + lg2[1][px][i]);
    mx = fmaxf(mx, __shfl_xor(mx, 1));
    mx = fmaxf(mx, __shfl_xor(mx, 2));
    mx = fmaxf(mx, __shfl_xor(mx, 4));
    mx = fmaxf(mx, __shfl_xor(mx, 8));
    float s = 0.f;
    for (int i = sub; i < 49; i += 16) {
      float v = __expf(lg2[0][px][i] + lg2[1][px][i] - mx);
      lg2[0][px][i] = v;                  // stash exp (same-lane RAW only)
      s += v;
    }
    s += __shfl_xor(s, 1);
    s += __shfl_xor(s, 2);
    s += __shfl_xor(s, 4);
    s += __shfl_xor(s, 8);
    const float inv = 1.f / s;
    for (int i = sub; i < 49; i += 16) {
      const int dh7 = i / 7, dw7 = i - dh7 * 7;
      pb[dh7][px][px + 5 + dw7] = f2bf(lg2[0][px][i] * inv);
    }
  }

  // ---------- phase 2: out[c][m'] = sum_n' v[c][n'] * P[m'][n'] ----------
  // LDS v tile: byte off = c*64 + ((po ^ ((c&3)^((c>>2)&3)))*16) + (px&7)*2
  f32x4 acc[4];
  #pragma unroll
  for (int i = 0; i < 4; ++i) acc[i] = (f32x4){0.f, 0.f, 0.f, 0.f};
  #pragma unroll 1
  for (int dh = 0; dh < 7; ++dh) {
    __syncthreads();                      // kst free (phase1 / prev iter done)
    #pragma unroll
    for (int it = 0; it < 4; ++it) {      // WRITEV (swizzled c-major tile)
      const int s = t + it * 256;
      const int c = s >> 2, po = s & 3;
      const int sc = (c & 3) ^ ((c >> 2) & 3);
      *(uint4*)(sk + c * 64 + ((po ^ sc) * 16)) = pv[it];
    }
    if (dh < 6) {                         // LOADV(dh+1)
      const int rdh1 = h + dh - 2;
      const bool rok2 = (rdh1 >= 0) && (rdh1 < 64);
      const int rdhc = rdh1 < 0 ? 0 : (rdh1 > 63 ? 63 : rdh1);
      const int rp = (b * 64 + rdhc) * 64;
      #pragma unroll
      for (int it = 0; it < 4; ++it) {
        const int s = t + it * 256;
        const int c = s >> 2, po = s & 3;
        const int w0 = wbase - 8 + po * 8;
        const int wc = w0 < 0 ? 0 : (w0 > 56 ? 56 : w0);
        const int g = c * 16384 + rp + wc;
        uint4 vv = *(const uint4*)(vo + g);
        const bool zz = (!rok2) | (w0 < 0) | (w0 > 56);
        pv[it].x = zz ? 0u : vv.x; pv[it].y = zz ? 0u : vv.y; pv[it].z = zz ? 0u : vv.z; pv[it].w = zz ? 0u : vv.w;
      }
    }
    __syncthreads();                      // tile visible
    #pragma unroll
    for (int i = 0; i < 4; ++i) {
      const int c = wv * 64 + i * 16 + l15;      // A: m = channel, k-octet = q4
      const int sc = (c & 3) ^ ((c >> 2) & 3);
      const short8 af = *(const short8*)(sk + c * 64 + ((q4 ^ sc) * 16));
      const short8 bf_ = *(const short8*)(&pb[dh][l15][q4 * 8]);
      acc[i] = __builtin_amdgcn_mfma_f32_16x16x32_bf16(af, bf_, acc[i], 0, 0, 0);
    }
  }
  #pragma unroll
  for (int i = 0; i < 4; ++i) {
    const int ct = wv * 4 + i;
    // D: row m = channel q4*4+r, col n = pixel l15 -> native [b][c][h][w]
    #pragma unroll
    for (int r = 0; r < 4; ++r)
      out[(b * 256 + ct * 16 + q4 * 4 + r) * 4096 + h * 64 + wbase + l15] = acc[i][r];
  }
}

extern "C" void kernel_launch(void* const* d_in, const int* in_sizes, int n_in,
                              void* d_out, int out_size, void* d_ws, size_t ws_size,
                              hipStream_t stream)
{
  const float* x  = (const float*)d_in[0];
  const float* w1 = (const float*)d_in[1];
  const float* w2 = (const float*)d_in[2];
  const float* w3 = (const float*)d_in[3];
  float* out = (float*)d_out;

  char* ws = (char*)d_ws;
  u32* qI = (u32*)ws;                      // 16 MB interleaved q (h|l<<16), pixel-major [pix][c]
  u32* kI = (u32*)(ws + (16u << 20));      // 16 MB interleaved k
  u16* vo = (u16*)(ws + (32u << 20));      // 8 MB bf16 v, c-major [o][pix]
  u16* Wh = (u16*)(ws + (40u << 20));      // 384 KB
  u16* Wl = Wh + 196608;                   // 384 KB

  wsplit<<<192, 256, 0, stream>>>(w1, w2, w3, Wh, Wl);
  qkv_gemm<<<dim3(128, 2, 3), 256, 0, stream>>>(x, Wh, Wl, qI, kI, vo);
  attn<<<dim3(1024), 256, 0, stream>>>(qI, kI, vo, out);
}

// Round 11
// 127.759 us; speedup vs baseline: 1.0187x; 1.0032x over previous
//
#include <hip/hip_runtime.h>

typedef unsigned short u16;
typedef unsigned int u32;
typedef __attribute__((ext_vector_type(8))) short short8;
typedef __attribute__((ext_vector_type(4))) float f32x4;

__device__ __forceinline__ float bf2f(u16 h){ return __builtin_bit_cast(float, ((u32)h) << 16); }
__device__ __forceinline__ u16 f2bf(float f){
  u32 u = __builtin_bit_cast(u32, f);
  u32 r = u + 0x7fffu + ((u >> 16) & 1u);
  return (u16)(r >> 16);
}
// byte offset of channel-octet `co` of tile-pixel `px` in a swizzled [px][256ch] bf16 LDS tile
__device__ __forceinline__ int swzb(int px, int co){
  return px * 512 + ((co * 16) ^ ((((px & 7) ^ ((px >> 3) * 3)) & 7) << 4));
}
// unpack 8 interleaved (h|l<<16) channel words (2 uint4) -> vh (8 bf16 hi), vl (8 bf16 lo)
__device__ __forceinline__ void unpk(const uint4 A, const uint4 B, uint4& vh, uint4& vl){
  vh.x = (A.x & 0xffffu) | (A.y << 16);  vl.x = (A.x >> 16) | (A.y & 0xffff0000u);
  vh.y = (A.z & 0xffffu) | (A.w << 16);  vl.y = (A.z >> 16) | (A.w & 0xffff0000u);
  vh.z = (B.x & 0xffffu) | (B.y << 16);  vl.z = (B.x >> 16) | (B.y & 0xffff0000u);
  vh.w = (B.z & 0xffffu) | (B.w << 16);  vl.w = (B.z >> 16) | (B.w & 0xffff0000u);
}

// ------- Kernel 0b: w1|w2|w3 fp32 [o][c] -> Wh/Wl bf16 hi/lo -------
__global__ __launch_bounds__(256) void wsplit(const float* __restrict__ w1,
                                              const float* __restrict__ w2,
                                              const float* __restrict__ w3,
                                              u16* __restrict__ Wh,
                                              u16* __restrict__ Wl)
{
  int i = (blockIdx.x * 256 + threadIdx.x) * 4;
  int z = i >> 16, off = i & 65535;
  const float* w = (z == 0) ? w1 : ((z == 1) ? w2 : w3);
  float4 v = *(const float4*)(w + off);
  u16 h0 = f2bf(v.x), h1 = f2bf(v.y), h2 = f2bf(v.z), h3 = f2bf(v.w);
  u16 l0 = f2bf(v.x - bf2f(h0)), l1 = f2bf(v.y - bf2f(h1));
  u16 l2 = f2bf(v.z - bf2f(h2)), l3 = f2bf(v.w - bf2f(h3));
  uint2 hv; hv.x = (u32)h0 | ((u32)h1 << 16); hv.y = (u32)h2 | ((u32)h3 << 16);
  uint2 lv; lv.x = (u32)l0 | ((u32)l1 << 16); lv.y = (u32)l2 | ((u32)l3 << 16);
  *(uint2*)(Wh + i) = hv;
  *(uint2*)(Wl + i) = lv;
}

// ------- Kernel 1: fused split+qkv. A staged directly from fp32 x.
// A-tile: [128 px][16 u32] (no pad), pair-granular XOR swizzle: u32-pair p of row r
// lives at r*16 + (p ^ ((r>>2)&7))*2. Thread owns (cq in [0,8), pq in [0,32)):
// 4 coalesced float4 loads (channels 4cq..4cq+3, pixels 4pq..4pq+3); per pixel one
// ds_write_b64 (4-way banks vs R10's 8-way b32 x16). Fragment read = 2x ds_read_b64
// (conflict-free). f2bf/MFMA order identical to R10 -> bit-identical numerics.
// B via global_load_lds (R4 pattern). Outputs unchanged. grid (128,2,3). -------
__global__ __launch_bounds__(256) void qkv_gemm(const float* __restrict__ x,
                                                const u16* __restrict__ Wh,
                                                const u16* __restrict__ Wl,
                                                u32* __restrict__ qI,
                                                u32* __restrict__ kI,
                                                u16* __restrict__ vo)
{
  __shared__ u16 lAh[128 * 32];
  __shared__ u16 lAl[128 * 32];
  __shared__ u16 lBh[128 * 32];
  __shared__ u16 lBl[128 * 32];
  const int z = blockIdx.z;
  const int t = threadIdx.x;
  const int lane = t & 63, wv = t >> 6;
  const int ln15 = lane & 15, q = lane >> 4;
  const int pix0 = blockIdx.x * 128;
  const int o0 = blockIdx.y * 128;
  const int pw = (wv >> 1) * 64, ow = (wv & 1) * 64;
  const int b = pix0 >> 12, hw0 = pix0 & 4095;
  f32x4 acc[4][4];
  #pragma unroll
  for (int i = 0; i < 4; ++i)
    #pragma unroll
    for (int j = 0; j < 4; ++j)
      acc[i][j] = (f32x4){0.f, 0.f, 0.f, 0.f};

  // ---- B staging geometry (R4-proven) ----
  const int Lr = lane >> 2;
  const int cswz = (lane & 3) ^ ((lane >> 3) & 3);
  const int r0 = wv * 32 + Lr;
  const int r1 = wv * 32 + 16 + Lr;
  const int gB0 = z * 65536 + (o0 + r0) * 256 + cswz * 8;
  const int gB1 = z * 65536 + (o0 + r1) * 256 + cswz * 8;
  const int s0 = wv * 1024;
  const int s1 = wv * 1024 + 512;
  const int qsw = (q ^ ((ln15 >> 1) & 3)) * 8;   // B read-side chunk swizzle (u16)

  // ---- A staging geometry: thread owns (channel-quad cq, pixel-quad pq) ----
  const int cq = t >> 5;                         // [0,8): channels 4cq..4cq+3 of K-slice
  const int pq = t & 31;                         // [0,32): pixels 4pq..4pq+3
  const int apw = cq ^ (pq & 7);                 // swizzled u32-pair index (write side)
  const float* xb = x + (b * 256) * 4096 + hw0;  // x[(b*256+c)*4096 + hw]
  u32* lAh32 = (u32*)lAh;
  u32* lAl32 = (u32*)lAl;

  float4 ax[4];   // prefetched A quads: channel 4cq+jc, pixels 4pq..4pq+3
  #pragma unroll
  for (int jc = 0; jc < 4; ++jc)
    ax[jc] = *(const float4*)(xb + (4 * cq + jc) * 4096 + pq * 4);

  for (int kc8 = 0; kc8 < 8; ++kc8) {
    __syncthreads();                    // previous K-step done reading LDS
    // B stage (fire-and-forget; drains at next barrier)
    __builtin_amdgcn_global_load_lds((const u32*)(Wh + gB0 + kc8 * 32), (u32*)(lBh + s0), 16, 0, 0);
    __builtin_amdgcn_global_load_lds((const u32*)(Wh + gB1 + kc8 * 32), (u32*)(lBh + s1), 16, 0, 0);
    if (z < 2) {
      __builtin_amdgcn_global_load_lds((const u32*)(Wl + gB0 + kc8 * 32), (u32*)(lBl + s0), 16, 0, 0);
      __builtin_amdgcn_global_load_lds((const u32*)(Wl + gB1 + kc8 * 32), (u32*)(lBl + s1), 16, 0, 0);
    }
    // A stage: fp32 quads -> hi/lo bf16, one b64 write per pixel per buffer
    #pragma unroll
    for (int j = 0; j < 4; ++j) {
      const int row = pq * 4 + j;
      const int woff = row * 16 + apw * 2;
      const float v0 = ax[0][j], v1 = ax[1][j], v2 = ax[2][j], v3 = ax[3][j];
      const u16 h0 = f2bf(v0), h1 = f2bf(v1), h2 = f2bf(v2), h3 = f2bf(v3);
      uint2 hw_; hw_.x = (u32)h0 | ((u32)h1 << 16); hw_.y = (u32)h2 | ((u32)h3 << 16);
      *(uint2*)(lAh32 + woff) = hw_;
      if (z < 2) {
        const u16 l0 = f2bf(v0 - bf2f(h0)), l1 = f2bf(v1 - bf2f(h1));
        const u16 l2 = f2bf(v2 - bf2f(h2)), l3 = f2bf(v3 - bf2f(h3));
        uint2 lw_; lw_.x = (u32)l0 | ((u32)l1 << 16); lw_.y = (u32)l2 | ((u32)l3 << 16);
        *(uint2*)(lAl32 + woff) = lw_;
      }
    }
    if (kc8 < 7) {                      // T14: prefetch A quads for next K-step
      const float* xn = xb + (kc8 + 1) * 32 * 4096;
      #pragma unroll
      for (int jc = 0; jc < 4; ++jc)
        ax[jc] = *(const float4*)(xn + (4 * cq + jc) * 4096 + pq * 4);
    }
    __syncthreads();                    // tiles visible (gload_lds drained, ds_writes done)
    short8 afh[4], bfh[4];
    #pragma unroll
    for (int i = 0; i < 4; ++i) {
      const int rowA = pw + i * 16 + ln15;
      const int hxr = (rowA >> 2) & 7;
      const int baseA = rowA * 16;
      const uint2 u0 = *(const uint2*)(lAh32 + baseA + ((2 * q) ^ hxr) * 2);
      const uint2 u1 = *(const uint2*)(lAh32 + baseA + ((2 * q + 1) ^ hxr) * 2);
      uint4 uu; uu.x = u0.x; uu.y = u0.y; uu.z = u1.x; uu.w = u1.y;
      afh[i] = __builtin_bit_cast(short8, uu);
    }
    #pragma unroll
    for (int j = 0; j < 4; ++j)
      bfh[j] = *(const short8*)(lBh + (ow + j * 16 + ln15) * 32 + qsw);
    #pragma unroll
    for (int i = 0; i < 4; ++i)
      #pragma unroll
      for (int j = 0; j < 4; ++j)
        acc[i][j] = __builtin_amdgcn_mfma_f32_16x16x32_bf16(afh[i], bfh[j], acc[i][j], 0, 0, 0);
    if (z < 2) {
      short8 afl[4], bfl[4];
      #pragma unroll
      for (int i = 0; i < 4; ++i) {
        const int rowA = pw + i * 16 + ln15;
        const int hxr = (rowA >> 2) & 7;
        const int baseA = rowA * 16;
        const uint2 u0 = *(const uint2*)(lAl32 + baseA + ((2 * q) ^ hxr) * 2);
        const uint2 u1 = *(const uint2*)(lAl32 + baseA + ((2 * q + 1) ^ hxr) * 2);
        uint4 uu; uu.x = u0.x; uu.y = u0.y; uu.z = u1.x; uu.w = u1.y;
        afl[i] = __builtin_bit_cast(short8, uu);
      }
      #pragma unroll
      for (int j = 0; j < 4; ++j)
        bfl[j] = *(const short8*)(lBl + (ow + j * 16 + ln15) * 32 + qsw);
      #pragma unroll
      for (int i = 0; i < 4; ++i)
        #pragma unroll
        for (int j = 0; j < 4; ++j) {
          acc[i][j] = __builtin_amdgcn_mfma_f32_16x16x32_bf16(afh[i], bfl[j], acc[i][j], 0, 0, 0);
          acc[i][j] = __builtin_amdgcn_mfma_f32_16x16x32_bf16(afl[i], bfh[j], acc[i][j], 0, 0, 0);
        }
    }
  }

  // D: m(pixel) = pw + i*16 + q*4 + r, n(o) = ow + j*16 + ln15
  if (z == 2) {
    // v: c-major [o][pix]; 4 acc regs = 4 consecutive pixels -> packed uint2 store
    #pragma unroll
    for (int i = 0; i < 4; ++i) {
      int pixb = pix0 + pw + i * 16 + q * 4;
      #pragma unroll
      for (int j = 0; j < 4; ++j) {
        int o = o0 + ow + j * 16 + ln15;
        u32 p0 = (u32)f2bf(acc[i][j][0]) | ((u32)f2bf(acc[i][j][1]) << 16);
        u32 p1 = (u32)f2bf(acc[i][j][2]) | ((u32)f2bf(acc[i][j][3]) << 16);
        uint2 pvv; pvv.x = p0; pvv.y = p1;
        *(uint2*)(vo + o * 16384 + pixb) = pvv;
      }
    }
  } else {
    u32* dst = (z == 0) ? qI : kI;
    #pragma unroll
    for (int i = 0; i < 4; ++i) {
      #pragma unroll
      for (int r = 0; r < 4; ++r) {
        int pix = pix0 + pw + i * 16 + q * 4 + r;
        int ob = o0 + ow + ln15;
        #pragma unroll
        for (int j = 0; j < 4; ++j) {
          float vv = acc[i][j][r];
          u16 hh = f2bf(vv);
          u16 ll = f2bf(vv - bf2f(hh));
          dst[pix * 256 + ob + j * 16] = (u32)hh | ((u32)ll << 16);
        }
      }
    }
  }
}

// ------- Kernel 2: banded-MFMA local attention (unchanged from R10). -------
__global__ __launch_bounds__(256, 4) void attn(const u32* __restrict__ qI,
                                               const u32* __restrict__ kI,
                                               const u16* __restrict__ vo,
                                               float* __restrict__ out)
{
  __shared__ u16 kst[12288];             // 24576 B: k hi @0, k lo @+12288B; q @0/+8192B; v tile @0 (16 KB)
  __shared__ float lg2[2][16][57];       // 7296 B
  __shared__ u16 pb[7][16][40];          // 8960 B   (total 40832 <= 40960 -> 4 blocks/CU)

  const int t = threadIdx.x;
  const int lane = t & 63, wv = t >> 6;
  const int l15 = lane & 15, q4 = lane >> 4;
  const int bid = ((int)blockIdx.x & 7) * 128 + ((int)blockIdx.x >> 3);  // XCD-bijective
  const int quarter = bid & 3;
  const int row = bid >> 2;               // b*64 + h
  const int b = row >> 6, h = row & 63;
  const int wbase = quarter * 16;
  char* sk = (char*)kst;

  for (int i = t; i < 2 * 16 * 57; i += 256) ((float*)lg2)[i] = 0.f;
  for (int i = t; i < 2240; i += 256) ((u32*)pb)[i] = 0u;

  // ---------- q stage (coalesced; unpack h/l then swzb write) ----------
  #pragma unroll
  for (int it = 0; it < 2; ++it) {
    const int s = t + it * 256;                 // 0..511
    const int px = s >> 5, co = s & 31;
    const u32* src = qI + (row * 64 + wbase + px) * 256 + co * 8;
    const uint4 A = ((const uint4*)src)[0];
    const uint4 B = ((const uint4*)src)[1];
    uint4 vh, vl; unpk(A, B, vh, vl);
    const int off = swzb(px, co);
    *(uint4*)(sk + off) = vh;
    *(uint4*)(sk + 8192 + off) = vl;
  }

  const int ch = wv >> 1, win = wv & 1;          // wave -> (c-half, n-window)
  uint4 pA[3], pB[3];                            // raw interleaved k prefetch
  // k prefetch for dh=0 (flies during barrier + q-frag reads)
  {
    const int rdh0 = h - 3;
    const int rdhc = rdh0 < 0 ? 0 : rdh0;
    const int rp = (b * 64 + rdhc) * 64;
    #pragma unroll
    for (int it = 0; it < 3; ++it) {
      const int s = t + it * 256;
      const int px = s >> 5, co = s & 31;
      const int w = wbase - 4 + px;
      const int wc = w < 0 ? 0 : (w > 63 ? 63 : w);
      const u32* src = kI + (rp + wc) * 256 + co * 8;
      uint4 A = ((const uint4*)src)[0];
      uint4 B = ((const uint4*)src)[1];
      const bool zz = (w < 0) | (w > 63);
      pA[it].x = zz ? 0u : A.x; pA[it].y = zz ? 0u : A.y; pA[it].z = zz ? 0u : A.z; pA[it].w = zz ? 0u : A.w;
      pB[it].x = zz ? 0u : B.x; pB[it].y = zz ? 0u : B.y; pB[it].z = zz ? 0u : B.z; pB[it].w = zz ? 0u : B.w;
    }
  }
  __syncthreads();

  // q fragments from LDS
  short8 qfh[4], qfl[4];
  #pragma unroll
  for (int u = 0; u < 4; ++u) {
    const int co = (ch * 4 + u) * 4 + q4;
    const int off = swzb(l15, co);
    qfh[u] = *(const short8*)(sk + off);
    qfl[u] = *(const short8*)(sk + 8192 + off);
  }

  // ---------- phase 1: logits ----------
  const int tidx = win ? (l15 + 12 > 23 ? 23 : l15 + 12) : (l15 - 4 < 0 ? 0 : l15 - 4);
  #pragma unroll 1
  for (int dh = 0; dh < 7; ++dh) {
    __syncthreads();                      // previous compute done reading kst
    #pragma unroll
    for (int it = 0; it < 3; ++it) {      // WRITEK (unpack + swzb write)
      const int s = t + it * 256;
      const int px = s >> 5, co = s & 31;
      uint4 vh, vl; unpk(pA[it], pB[it], vh, vl);
      const int off = swzb(px, co);
      *(uint4*)(sk + off) = vh;
      *(uint4*)(sk + 12288 + off) = vl;
    }
    if (dh < 6) {                         // LOADK(dh+1): flies during compute
      const int rdh1 = h + dh - 2;
      const int rdhc = rdh1 < 0 ? 0 : (rdh1 > 63 ? 63 : rdh1);
      const int rp = (b * 64 + rdhc) * 64;
      #pragma unroll
      for (int it = 0; it < 3; ++it) {
        const int s = t + it * 256;
        const int px = s >> 5, co = s & 31;
        const int w = wbase - 4 + px;
        const int wc = w < 0 ? 0 : (w > 63 ? 63 : w);
        const u32* src = kI + (rp + wc) * 256 + co * 8;
        uint4 A = ((const uint4*)src)[0];
        uint4 B = ((const uint4*)src)[1];
        const bool zz = (w < 0) | (w > 63);
        pA[it].x = zz ? 0u : A.x; pA[it].y = zz ? 0u : A.y; pA[it].z = zz ? 0u : A.z; pA[it].w = zz ? 0u : A.w;
        pB[it].x = zz ? 0u : B.x; pB[it].y = zz ? 0u : B.y; pB[it].z = zz ? 0u : B.z; pB[it].w = zz ? 0u : B.w;
      }
    }
    __syncthreads();                      // staged tile visible
    const int rdh = h + dh - 3;
    const bool rok = (rdh >= 0) && (rdh < 64);
    f32x4 a0 = {0.f, 0.f, 0.f, 0.f};
    f32x4 a1 = {0.f, 0.f, 0.f, 0.f};     // split chains for MFMA ILP
    #pragma unroll
    for (int u = 0; u < 4; ++u) {
      const int co = (ch * 4 + u) * 4 + q4;
      const int off = swzb(tidx, co);
      const short8 bh_ = *(const short8*)(sk + off);
      const short8 bl_ = *(const short8*)(sk + 12288 + off);
      a0 = __builtin_amdgcn_mfma_f32_16x16x32_bf16(qfh[u], bh_, a0, 0, 0, 0);
      a1 = __builtin_amdgcn_mfma_f32_16x16x32_bf16(qfh[u], bl_, a1, 0, 0, 0);
      a0 = __builtin_amdgcn_mfma_f32_16x16x32_bf16(qfl[u], bh_, a0, 0, 0, 0);
    }
    // scatter band entries: D col n=l15, row m=q4*4+r; dw = n_w - m_w + 3
    #pragma unroll
    for (int r = 0; r < 4; ++r) {
      const int mloc = q4 * 4 + r;
      const int dw = l15 - mloc - 5 + win * 16;
      if (rok && dw >= 0 && dw < 7) lg2[ch][mloc][dh * 7 + dw] = a0[r] + a1[r];
    }
  }

  // v prefetch for dh=0 (c-major vo[o*16384+pix]; flies during softmax)
  uint4 pv[4];
  {
    const int rdh0 = h - 3;
    const bool rok2 = rdh0 >= 0;
    const int rdhc = rdh0 < 0 ? 0 : rdh0;
    const int rp = (b * 64 + rdhc) * 64;
    #pragma unroll
    for (int it = 0; it < 4; ++it) {
      const int s = t + it * 256;                // 0..1023
      const int c = s >> 2, po = s & 3;          // channel, px-octet
      const int w0 = wbase - 8 + po * 8;
      const int wc = w0 < 0 ? 0 : (w0 > 56 ? 56 : w0);
      const int g = c * 16384 + rp + wc;
      uint4 vv = *(const uint4*)(vo + g);
      const bool zz = (!rok2) | (w0 < 0) | (w0 > 56);
      pv[it].x = zz ? 0u : vv.x; pv[it].y = zz ? 0u : vv.y; pv[it].z = zz ? 0u : vv.z; pv[it].w = zz ? 0u : vv.w;
    }
  }
  __syncthreads();

  // ---------- softmax: 16 lanes per pixel ----------
  {
    const int px = t >> 4, sub = t & 15;
    float mx = -3.0e38f;
    for (int i = sub; i < 49; i += 16)
      mx = fmaxf(mx, lg2[0][px][i] + lg2[1][px][i]);
    mx = fmaxf(mx, __shfl_xor(mx, 1));
    mx = fmaxf(mx, __shfl_xor(mx, 2));
    mx = fmaxf(mx, __shfl_xor(mx, 4));
    mx = fmaxf(mx, __shfl_xor(mx, 8));
    float s = 0.f;
    for (int i = sub; i < 49; i += 16) {
      float v = __expf(lg2[0][px][i] + lg2[1][px][i] - mx);
      lg2[0][px][i] = v;                  // stash exp (same-lane RAW only)
      s += v;
    }
    s += __shfl_xor(s, 1);
    s += __shfl_xor(s, 2);
    s += __shfl_xor(s, 4);
    s += __shfl_xor(s, 8);
    const float inv = 1.f / s;
    for (int i = sub; i < 49; i += 16) {
      const int dh7 = i / 7, dw7 = i - dh7 * 7;
      pb[dh7][px][px + 5 + dw7] = f2bf(lg2[0][px][i] * inv);
    }
  }

  // ---------- phase 2: out[c][m'] = sum_n' v[c][n'] * P[m'][n'] ----------
  // LDS v tile: byte off = c*64 + ((po ^ ((c&3)^((c>>2)&3)))*16) + (px&7)*2
  f32x4 acc[4];
  #pragma unroll
  for (int i = 0; i < 4; ++i) acc[i] = (f32x4){0.f, 0.f, 0.f, 0.f};
  #pragma unroll 1
  for (int dh = 0; dh < 7; ++dh) {
    __syncthreads();                      // kst free (phase1 / prev iter done)
    #pragma unroll
    for (int it = 0; it < 4; ++it) {      // WRITEV (swizzled c-major tile)
      const int s = t + it * 256;
      const int c = s >> 2, po = s & 3;
      const int sc = (c & 3) ^ ((c >> 2) & 3);
      *(uint4*)(sk + c * 64 + ((po ^ sc) * 16)) = pv[it];
    }
    if (dh < 6) {                         // LOADV(dh+1)
      const int rdh1 = h + dh - 2;
      const bool rok2 = (rdh1 >= 0) && (rdh1 < 64);
      const int rdhc = rdh1 < 0 ? 0 : (rdh1 > 63 ? 63 : rdh1);
      const int rp = (b * 64 + rdhc) * 64;
      #pragma unroll
      for (int it = 0; it < 4; ++it) {
        const int s = t + it * 256;
        const int c = s >> 2, po = s & 3;
        const int w0 = wbase - 8 + po * 8;
        const int wc = w0 < 0 ? 0 : (w0 > 56 ? 56 : w0);
        const int g = c * 16384 + rp + wc;
        uint4 vv = *(const uint4*)(vo + g);
        const bool zz = (!rok2) | (w0 < 0) | (w0 > 56);
        pv[it].x = zz ? 0u : vv.x; pv[it].y = zz ? 0u : vv.y; pv[it].z = zz ? 0u : vv.z; pv[it].w = zz ? 0u : vv.w;
      }
    }
    __syncthreads();                      // tile visible
    #pragma unroll
    for (int i = 0; i < 4; ++i) {
      const int c = wv * 64 + i * 16 + l15;      // A: m = channel, k-octet = q4
      const int sc = (c & 3) ^ ((c >> 2) & 3);
      const short8 af = *(const short8*)(sk + c * 64 + ((q4 ^ sc) * 16));
      const short8 bf_ = *(const short8*)(&pb[dh][l15][q4 * 8]);
      acc[i] = __builtin_amdgcn_mfma_f32_16x16x32_bf16(af, bf_, acc[i], 0, 0, 0);
    }
  }
  #pragma unroll
  for (int i = 0; i < 4; ++i) {
    const int ct = wv * 4 + i;
    // D: row m = channel q4*4+r, col n = pixel l15 -> native [b][c][h][w]
    #pragma unroll
    for (int r = 0; r < 4; ++r)
      out[(b * 256 + ct * 16 + q4 * 4 + r) * 4096 + h * 64 + wbase + l15] = acc[i][r];
  }
}

extern "C" void kernel_launch(void* const* d_in, const int* in_sizes, int n_in,
                              void* d_out, int out_size, void* d_ws, size_t ws_size,
                              hipStream_t stream)
{
  const float* x  = (const float*)d_in[0];
  const float* w1 = (const float*)d_in[1];
  const float* w2 = (const float*)d_in[2];
  const float* w3 = (const float*)d_in[3];
  float* out = (float*)d_out;

  char* ws = (char*)d_ws;
  u32* qI = (u32*)ws;                      // 16 MB interleaved q (h|l<<16), pixel-major [pix][c]
  u32* kI = (u32*)(ws + (16u << 20));      // 16 MB interleaved k
  u16* vo = (u16*)(ws + (32u << 20));      // 8 MB bf16 v, c-major [o][pix]
  u16* Wh = (u16*)(ws + (40u << 20));      // 384 KB
  u16* Wl = Wh + 196608;                   // 384 KB

  wsplit<<<192, 256, 0, stream>>>(w1, w2, w3, Wh, Wl);
  qkv_gemm<<<dim3(128, 2, 3), 256, 0, stream>>>(x, Wh, Wl, qI, kI, vo);
  attn<<<dim3(1024), 256, 0, stream>>>(qI, kI, vo, out);
}

// Round 12
// 126.228 us; speedup vs baseline: 1.0311x; 1.0121x over previous
//
#include <hip/hip_runtime.h>

typedef unsigned short u16;
typedef unsigned int u32;
typedef __attribute__((ext_vector_type(8))) short short8;
typedef __attribute__((ext_vector_type(4))) float f32x4;

__device__ __forceinline__ float bf2f(u16 h){ return __builtin_bit_cast(float, ((u32)h) << 16); }
__device__ __forceinline__ u16 f2bf(float f){
  u32 u = __builtin_bit_cast(u32, f);
  u32 r = u + 0x7fffu + ((u >> 16) & 1u);
  return (u16)(r >> 16);
}
// byte offset of channel-octet `co` of tile-pixel `px` in a swizzled [px][256ch] bf16 LDS tile
__device__ __forceinline__ int swzb(int px, int co){
  return px * 512 + ((co * 16) ^ ((((px & 7) ^ ((px >> 3) * 3)) & 7) << 4));
}
__device__ __forceinline__ int fpx(int px){ return ((px & 7) ^ ((px >> 3) * 3)) & 7; }

// ------- Kernel 0b: w1|w2|w3 fp32 [o][c] -> Wh/Wl bf16 hi/lo; block 0 zeros the pad page -------
__global__ __launch_bounds__(256) void wsplit(const float* __restrict__ w1,
                                              const float* __restrict__ w2,
                                              const float* __restrict__ w3,
                                              u16* __restrict__ Wh,
                                              u16* __restrict__ Wl,
                                              u32* __restrict__ zp)
{
  if (blockIdx.x == 0) zp[threadIdx.x] = 0u;    // 1 KB zero page for OOB gload_lds sources
  int i = (blockIdx.x * 256 + threadIdx.x) * 4;
  int z = i >> 16, off = i & 65535;
  const float* w = (z == 0) ? w1 : ((z == 1) ? w2 : w3);
  float4 v = *(const float4*)(w + off);
  u16 h0 = f2bf(v.x), h1 = f2bf(v.y), h2 = f2bf(v.z), h3 = f2bf(v.w);
  u16 l0 = f2bf(v.x - bf2f(h0)), l1 = f2bf(v.y - bf2f(h1));
  u16 l2 = f2bf(v.z - bf2f(h2)), l3 = f2bf(v.w - bf2f(h3));
  uint2 hv; hv.x = (u32)h0 | ((u32)h1 << 16); hv.y = (u32)h2 | ((u32)h3 << 16);
  uint2 lv; lv.x = (u32)l0 | ((u32)l1 << 16); lv.y = (u32)l2 | ((u32)l3 << 16);
  *(uint2*)(Wh + i) = hv;
  *(uint2*)(Wl + i) = lv;
}

// ------- Kernel 1: fused split+qkv (R11 structure). A staged directly from fp32 x with
// pair-XOR-swizzled b64 writes; B via global_load_lds. Outputs: q/k hi/lo as 4 separate
// pixel-major bf16 arrays (R8 epilogue); v c-major [o][pix]. grid (128,2,3). -------
__global__ __launch_bounds__(256) void qkv_gemm(const float* __restrict__ x,
                                                const u16* __restrict__ Wh,
                                                const u16* __restrict__ Wl,
                                                u16* __restrict__ qh_, u16* __restrict__ ql_,
                                                u16* __restrict__ kh_, u16* __restrict__ kl_,
                                                u16* __restrict__ vo)
{
  __shared__ u16 lAh[128 * 32];
  __shared__ u16 lAl[128 * 32];
  __shared__ u16 lBh[128 * 32];
  __shared__ u16 lBl[128 * 32];
  const int z = blockIdx.z;
  const int t = threadIdx.x;
  const int lane = t & 63, wv = t >> 6;
  const int ln15 = lane & 15, q = lane >> 4;
  const int pix0 = blockIdx.x * 128;
  const int o0 = blockIdx.y * 128;
  const int pw = (wv >> 1) * 64, ow = (wv & 1) * 64;
  const int b = pix0 >> 12, hw0 = pix0 & 4095;
  f32x4 acc[4][4];
  #pragma unroll
  for (int i = 0; i < 4; ++i)
    #pragma unroll
    for (int j = 0; j < 4; ++j)
      acc[i][j] = (f32x4){0.f, 0.f, 0.f, 0.f};

  // ---- B staging geometry (R4-proven) ----
  const int Lr = lane >> 2;
  const int cswz = (lane & 3) ^ ((lane >> 3) & 3);
  const int r0 = wv * 32 + Lr;
  const int r1 = wv * 32 + 16 + Lr;
  const int gB0 = z * 65536 + (o0 + r0) * 256 + cswz * 8;
  const int gB1 = z * 65536 + (o0 + r1) * 256 + cswz * 8;
  const int s0 = wv * 1024;
  const int s1 = wv * 1024 + 512;
  const int qsw = (q ^ ((ln15 >> 1) & 3)) * 8;   // B read-side chunk swizzle (u16)

  // ---- A staging geometry: thread owns (channel-quad cq, pixel-quad pq) ----
  const int cq = t >> 5;                         // [0,8): channels 4cq..4cq+3 of K-slice
  const int pq = t & 31;                         // [0,32): pixels 4pq..4pq+3
  const int apw = cq ^ (pq & 7);                 // swizzled u32-pair index (write side)
  const float* xb = x + (b * 256) * 4096 + hw0;  // x[(b*256+c)*4096 + hw]
  u32* lAh32 = (u32*)lAh;
  u32* lAl32 = (u32*)lAl;

  float4 ax[4];   // prefetched A quads: channel 4cq+jc, pixels 4pq..4pq+3
  #pragma unroll
  for (int jc = 0; jc < 4; ++jc)
    ax[jc] = *(const float4*)(xb + (4 * cq + jc) * 4096 + pq * 4);

  for (int kc8 = 0; kc8 < 8; ++kc8) {
    __syncthreads();                    // previous K-step done reading LDS
    // B stage (fire-and-forget; drains at next barrier)
    __builtin_amdgcn_global_load_lds((const u32*)(Wh + gB0 + kc8 * 32), (u32*)(lBh + s0), 16, 0, 0);
    __builtin_amdgcn_global_load_lds((const u32*)(Wh + gB1 + kc8 * 32), (u32*)(lBh + s1), 16, 0, 0);
    if (z < 2) {
      __builtin_amdgcn_global_load_lds((const u32*)(Wl + gB0 + kc8 * 32), (u32*)(lBl + s0), 16, 0, 0);
      __builtin_amdgcn_global_load_lds((const u32*)(Wl + gB1 + kc8 * 32), (u32*)(lBl + s1), 16, 0, 0);
    }
    // A stage: fp32 quads -> hi/lo bf16, one b64 write per pixel per buffer
    #pragma unroll
    for (int j = 0; j < 4; ++j) {
      const int row = pq * 4 + j;
      const int woff = row * 16 + apw * 2;
      const float v0 = ax[0][j], v1 = ax[1][j], v2 = ax[2][j], v3 = ax[3][j];
      const u16 h0 = f2bf(v0), h1 = f2bf(v1), h2 = f2bf(v2), h3 = f2bf(v3);
      uint2 hw_; hw_.x = (u32)h0 | ((u32)h1 << 16); hw_.y = (u32)h2 | ((u32)h3 << 16);
      *(uint2*)(lAh32 + woff) = hw_;
      if (z < 2) {
        const u16 l0 = f2bf(v0 - bf2f(h0)), l1 = f2bf(v1 - bf2f(h1));
        const u16 l2 = f2bf(v2 - bf2f(h2)), l3 = f2bf(v3 - bf2f(h3));
        uint2 lw_; lw_.x = (u32)l0 | ((u32)l1 << 16); lw_.y = (u32)l2 | ((u32)l3 << 16);
        *(uint2*)(lAl32 + woff) = lw_;
      }
    }
    if (kc8 < 7) {                      // T14: prefetch A quads for next K-step
      const float* xn = xb + (kc8 + 1) * 32 * 4096;
      #pragma unroll
      for (int jc = 0; jc < 4; ++jc)
        ax[jc] = *(const float4*)(xn + (4 * cq + jc) * 4096 + pq * 4);
    }
    __syncthreads();                    // tiles visible (gload_lds drained, ds_writes done)
    short8 afh[4], bfh[4];
    #pragma unroll
    for (int i = 0; i < 4; ++i) {
      const int rowA = pw + i * 16 + ln15;
      const int hxr = (rowA >> 2) & 7;
      const int baseA = rowA * 16;
      const uint2 u0 = *(const uint2*)(lAh32 + baseA + ((2 * q) ^ hxr) * 2);
      const uint2 u1 = *(const uint2*)(lAh32 + baseA + ((2 * q + 1) ^ hxr) * 2);
      uint4 uu; uu.x = u0.x; uu.y = u0.y; uu.z = u1.x; uu.w = u1.y;
      afh[i] = __builtin_bit_cast(short8, uu);
    }
    #pragma unroll
    for (int j = 0; j < 4; ++j)
      bfh[j] = *(const short8*)(lBh + (ow + j * 16 + ln15) * 32 + qsw);
    #pragma unroll
    for (int i = 0; i < 4; ++i)
      #pragma unroll
      for (int j = 0; j < 4; ++j)
        acc[i][j] = __builtin_amdgcn_mfma_f32_16x16x32_bf16(afh[i], bfh[j], acc[i][j], 0, 0, 0);
    if (z < 2) {
      short8 afl[4], bfl[4];
      #pragma unroll
      for (int i = 0; i < 4; ++i) {
        const int rowA = pw + i * 16 + ln15;
        const int hxr = (rowA >> 2) & 7;
        const int baseA = rowA * 16;
        const uint2 u0 = *(const uint2*)(lAl32 + baseA + ((2 * q) ^ hxr) * 2);
        const uint2 u1 = *(const uint2*)(lAl32 + baseA + ((2 * q + 1) ^ hxr) * 2);
        uint4 uu; uu.x = u0.x; uu.y = u0.y; uu.z = u1.x; uu.w = u1.y;
        afl[i] = __builtin_bit_cast(short8, uu);
      }
      #pragma unroll
      for (int j = 0; j < 4; ++j)
        bfl[j] = *(const short8*)(lBl + (ow + j * 16 + ln15) * 32 + qsw);
      #pragma unroll
      for (int i = 0; i < 4; ++i)
        #pragma unroll
        for (int j = 0; j < 4; ++j) {
          acc[i][j] = __builtin_amdgcn_mfma_f32_16x16x32_bf16(afh[i], bfl[j], acc[i][j], 0, 0, 0);
          acc[i][j] = __builtin_amdgcn_mfma_f32_16x16x32_bf16(afl[i], bfh[j], acc[i][j], 0, 0, 0);
        }
    }
  }

  // D: m(pixel) = pw + i*16 + q*4 + r, n(o) = ow + j*16 + ln15
  if (z == 2) {
    // v: c-major [o][pix]; 4 acc regs = 4 consecutive pixels -> packed uint2 store
    #pragma unroll
    for (int i = 0; i < 4; ++i) {
      int pixb = pix0 + pw + i * 16 + q * 4;
      #pragma unroll
      for (int j = 0; j < 4; ++j) {
        int o = o0 + ow + j * 16 + ln15;
        u32 p0 = (u32)f2bf(acc[i][j][0]) | ((u32)f2bf(acc[i][j][1]) << 16);
        u32 p1 = (u32)f2bf(acc[i][j][2]) | ((u32)f2bf(acc[i][j][3]) << 16);
        uint2 pvv; pvv.x = p0; pvv.y = p1;
        *(uint2*)(vo + o * 16384 + pixb) = pvv;
      }
    }
  } else {
    u16* dsth = (z == 0) ? qh_ : kh_;
    u16* dstl = (z == 0) ? ql_ : kl_;
    #pragma unroll
    for (int i = 0; i < 4; ++i) {
      #pragma unroll
      for (int r = 0; r < 4; ++r) {
        int pix = pix0 + pw + i * 16 + q * 4 + r;
        int ob = o0 + ow + ln15;
        #pragma unroll
        for (int j = 0; j < 4; ++j) {
          float vv = acc[i][j][r];
          u16 hh = f2bf(vv);
          u16 ll = f2bf(vv - bf2f(hh));
          dsth[pix * 256 + ob + j * 16] = hh;
          dstl[pix * 256 + ob + j * 16] = ll;
        }
      }
    }
  }
}

// ------- Kernel 2: banded-MFMA local attention. ALL LDS staging via global_load_lds:
// linear destinations + inverse-swizzled per-lane SOURCE addresses (G21/m173 pattern)
// reproduce the exact swzb / sc layouts; OOB lanes read a zeroed global page (zp) so
// staged zeros (required by 'SAME' padding semantics) are bit-identical to before.
// Fragment reads unchanged. Block = quarter row (16 q-px), 4 blocks/CU. -------
__global__ __launch_bounds__(256, 4) void attn(const u16* __restrict__ qh_,
                                               const u16* __restrict__ ql_,
                                               const u16* __restrict__ kh_,
                                               const u16* __restrict__ kl_,
                                               const u16* __restrict__ vo,
                                               const u16* __restrict__ zp,
                                               float* __restrict__ out)
{
  __shared__ u16 kst[12288];             // 24576 B: k hi @0, k lo @+12288B; q hi@0/lo@+8192B; v @0 (16 KB)
  __shared__ float lg2[2][16][57];       // 7296 B
  __shared__ u16 pb[7][16][40];          // 8960 B   (total 40832 <= 40960 -> 4 blocks/CU)

  const int t = threadIdx.x;
  const int lane = t & 63, wv = t >> 6;
  const int l15 = lane & 15, q4 = lane >> 4;
  const int bid = ((int)blockIdx.x & 7) * 128 + ((int)blockIdx.x >> 3);  // XCD-bijective
  const int quarter = bid & 3;
  const int row = bid >> 2;               // b*64 + h
  const int b = row >> 6, h = row & 63;
  const int wbase = quarter * 16;
  char* sk = (char*)kst;

  for (int i = t; i < 2 * 16 * 57; i += 256) ((float*)lg2)[i] = 0.f;
  for (int i = t; i < 2240; i += 256) ((u32*)pb)[i] = 0u;

  // ---------- q stage: gload_lds, linear dest + inverse-swizzled source ----------
  #pragma unroll
  for (int it = 0; it < 2; ++it) {
    const int px = it * 8 + (t >> 5);
    const int co = (t & 31) ^ fpx(px);
    const int g = (row * 64 + wbase + px) * 256 + co * 8;
    __builtin_amdgcn_global_load_lds((const u32*)(qh_ + g), (u32*)(sk + it * 4096 + wv * 1024), 16, 0, 0);
    __builtin_amdgcn_global_load_lds((const u32*)(ql_ + g), (u32*)(sk + 8192 + it * 4096 + wv * 1024), 16, 0, 0);
  }
  __syncthreads();                       // q landed (vmcnt drained at barrier)

  const int ch = wv >> 1, win = wv & 1;  // wave -> (c-half, n-window)
  // q fragments from LDS (unchanged layout)
  short8 qfh[4], qfl[4];
  #pragma unroll
  for (int u = 0; u < 4; ++u) {
    const int co = (ch * 4 + u) * 4 + q4;
    const int off = swzb(l15, co);
    qfh[u] = *(const short8*)(sk + off);
    qfl[u] = *(const short8*)(sk + 8192 + off);
  }
  __syncthreads();                       // all waves done reading q from sk

  // ---------- phase 1: logits ----------
  const int tidx = win ? (l15 + 12 > 23 ? 23 : l15 + 12) : (l15 - 4 < 0 ? 0 : l15 - 4);
  #pragma unroll 1
  for (int dh = 0; dh < 7; ++dh) {
    const int rdh = h + dh - 3;
    const bool rok = (rdh >= 0) && (rdh < 64);
    const int rp = (b * 64 + (rdh < 0 ? 0 : (rdh > 63 ? 63 : rdh))) * 64;
    // GLOADK(dh): k hi+lo, OOB lanes source the zero page
    #pragma unroll
    for (int it = 0; it < 3; ++it) {
      const int px = it * 8 + (t >> 5);
      const int co = (t & 31) ^ fpx(px);
      const int w = wbase - 4 + px;
      const bool ok = rok && (w >= 0) && (w < 64);
      const int g = (rp + (w < 0 ? 0 : (w > 63 ? 63 : w))) * 256 + co * 8;
      const u16* sh = ok ? kh_ + g : zp;
      const u16* sl = ok ? kl_ + g : zp;
      __builtin_amdgcn_global_load_lds((const u32*)sh, (u32*)(sk + it * 4096 + wv * 1024), 16, 0, 0);
      __builtin_amdgcn_global_load_lds((const u32*)sl, (u32*)(sk + 12288 + it * 4096 + wv * 1024), 16, 0, 0);
    }
    __syncthreads();                     // k landed
    f32x4 a0 = {0.f, 0.f, 0.f, 0.f};
    f32x4 a1 = {0.f, 0.f, 0.f, 0.f};     // split chains for MFMA ILP
    #pragma unroll
    for (int u = 0; u < 4; ++u) {
      const int co = (ch * 4 + u) * 4 + q4;
      const int off = swzb(tidx, co);
      const short8 bh_ = *(const short8*)(sk + off);
      const short8 bl_ = *(const short8*)(sk + 12288 + off);
      a0 = __builtin_amdgcn_mfma_f32_16x16x32_bf16(qfh[u], bh_, a0, 0, 0, 0);
      a1 = __builtin_amdgcn_mfma_f32_16x16x32_bf16(qfh[u], bl_, a1, 0, 0, 0);
      a0 = __builtin_amdgcn_mfma_f32_16x16x32_bf16(qfl[u], bh_, a0, 0, 0, 0);
    }
    // scatter band entries: D col n=l15, row m=q4*4+r; dw = n_w - m_w + 3
    #pragma unroll
    for (int r = 0; r < 4; ++r) {
      const int mloc = q4 * 4 + r;
      const int dw = l15 - mloc - 5 + win * 16;
      if (rok && dw >= 0 && dw < 7) lg2[ch][mloc][dh * 7 + dw] = a0[r] + a1[r];
    }
    __syncthreads();                     // all waves done reading k before next GLOADK
  }

  // ---------- softmax: 16 lanes per pixel (reads lg2/pb only; no sk hazard) ----------
  {
    const int px = t >> 4, sub = t & 15;
    float mx = -3.0e38f;
    for (int i = sub; i < 49; i += 16)
      mx = fmaxf(mx, lg2[0][px][i] + lg2[1][px][i]);
    mx = fmaxf(mx, __shfl_xor(mx, 1));
    mx = fmaxf(mx, __shfl_xor(mx, 2));
    mx = fmaxf(mx, __shfl_xor(mx, 4));
    mx = fmaxf(mx, __shfl_xor(mx, 8));
    float s = 0.f;
    for (int i = sub; i < 49; i += 16) {
      float v = __expf(lg2[0][px][i] + lg2[1][px][i] - mx);
      lg2[0][px][i] = v;                  // stash exp (same-lane RAW only)
      s += v;
    }
    s += __shfl_xor(s, 1);
    s += __shfl_xor(s, 2);
    s += __shfl_xor(s, 4);
    s += __shfl_xor(s, 8);
    const float inv = 1.f / s;
    for (int i = sub; i < 49; i += 16) {
      const int dh7 = i / 7, dw7 = i - dh7 * 7;
      pb[dh7][px][px + 5 + dw7] = f2bf(lg2[0][px][i] * inv);
    }
  }

  // ---------- phase 2: out[c][m'] = sum_n' v[c][n'] * P[m'][n'] ----------
  // v tile [256c][32px], sc-swizzled; staged via gload_lds with inverse-swizzled source.
  f32x4 acc[4];
  #pragma unroll
  for (int i = 0; i < 4; ++i) acc[i] = (f32x4){0.f, 0.f, 0.f, 0.f};
  #pragma unroll 1
  for (int dh = 0; dh < 7; ++dh) {
    const int rdh = h + dh - 3;
    const bool rok2 = (rdh >= 0) && (rdh < 64);
    const int rp = (b * 64 + (rdh < 0 ? 0 : (rdh > 63 ? 63 : rdh))) * 64;
    #pragma unroll
    for (int it = 0; it < 4; ++it) {     // GLOADV(dh)
      const int c = it * 64 + (t >> 2);
      const int sc = (c & 3) ^ ((c >> 2) & 3);
      const int po = (t & 3) ^ sc;
      const int w0 = wbase - 8 + po * 8;
      const bool ok = rok2 && (w0 >= 0) && (w0 <= 56);
      const u16* sv = ok ? vo + c * 16384 + rp + (w0 < 0 ? 0 : (w0 > 56 ? 56 : w0)) : zp;
      __builtin_amdgcn_global_load_lds((const u32*)sv, (u32*)(sk + it * 4096 + wv * 1024), 16, 0, 0);
    }
    __syncthreads();                     // v landed (+ pb visible for dh=0)
    #pragma unroll
    for (int i = 0; i < 4; ++i) {
      const int c = wv * 64 + i * 16 + l15;      // A: m = channel, k-octet = q4
      const int sc = (c & 3) ^ ((c >> 2) & 3);
      const short8 af = *(const short8*)(sk + c * 64 + ((q4 ^ sc) * 16));
      const short8 bf_ = *(const short8*)(&pb[dh][l15][q4 * 8]);
      acc[i] = __builtin_amdgcn_mfma_f32_16x16x32_bf16(af, bf_, acc[i], 0, 0, 0);
    }
    __syncthreads();                     // all waves done reading v before next GLOADV
  }
  #pragma unroll
  for (int i = 0; i < 4; ++i) {
    const int ct = wv * 4 + i;
    // D: row m = channel q4*4+r, col n = pixel l15 -> native [b][c][h][w]
    #pragma unroll
    for (int r = 0; r < 4; ++r)
      out[(b * 256 + ct * 16 + q4 * 4 + r) * 4096 + h * 64 + wbase + l15] = acc[i][r];
  }
}

extern "C" void kernel_launch(void* const* d_in, const int* in_sizes, int n_in,
                              void* d_out, int out_size, void* d_ws, size_t ws_size,
                              hipStream_t stream)
{
  const float* x  = (const float*)d_in[0];
  const float* w1 = (const float*)d_in[1];
  const float* w2 = (const float*)d_in[2];
  const float* w3 = (const float*)d_in[3];
  float* out = (float*)d_out;

  char* ws = (char*)d_ws;
  u16* qh_ = (u16*)ws;                     // 8 MB bf16 hi(q), pixel-major [pix][c]
  u16* ql_ = (u16*)(ws + (8u  << 20));     // 8 MB bf16 lo(q)
  u16* kh_ = (u16*)(ws + (16u << 20));     // 8 MB bf16 hi(k)
  u16* kl_ = (u16*)(ws + (24u << 20));     // 8 MB bf16 lo(k)
  u16* vo  = (u16*)(ws + (32u << 20));     // 8 MB bf16 v, c-major [o][pix]
  u16* Wh  = (u16*)(ws + (40u << 20));     // 384 KB
  u16* Wl  = Wh + 196608;                  // 384 KB
  u32* zp  = (u32*)(ws + (41u << 20));     // 1 KB zero page (zeroed by wsplit)

  wsplit<<<192, 256, 0, stream>>>(w1, w2, w3, Wh, Wl, zp);
  qkv_gemm<<<dim3(128, 2, 3), 256, 0, stream>>>(x, Wh, Wl, qh_, ql_, kh_, kl_, vo);
  attn<<<dim3(1024), 256, 0, stream>>>(qh_, ql_, kh_, kl_, vo, (const u16*)zp, out);
}

// Round 13
// 123.965 us; speedup vs baseline: 1.0499x; 1.0183x over previous
//
#include <hip/hip_runtime.h>

typedef unsigned short u16;
typedef unsigned int u32;
typedef __attribute__((ext_vector_type(8))) short short8;
typedef __attribute__((ext_vector_type(4))) float f32x4;

__device__ __forceinline__ float bf2f(u16 h){ return __builtin_bit_cast(float, ((u32)h) << 16); }
__device__ __forceinline__ u16 f2bf(float f){
  u32 u = __builtin_bit_cast(u32, f);
  u32 r = u + 0x7fffu + ((u >> 16) & 1u);
  return (u16)(r >> 16);
}
// byte offset of channel-octet `co` of tile-pixel `px` in a swizzled [px][256ch] bf16 LDS tile
__device__ __forceinline__ int swzb(int px, int co){
  return px * 512 + ((co * 16) ^ ((((px & 7) ^ ((px >> 3) * 3)) & 7) << 4));
}
__device__ __forceinline__ int fpx(int px){ return ((px & 7) ^ ((px >> 3) * 3)) & 7; }

// ------- Kernel 0b: w1|w2|w3 fp32 [o][c] -> Wh/Wl bf16 hi/lo; block 0 zeros the pad page -------
__global__ __launch_bounds__(256) void wsplit(const float* __restrict__ w1,
                                              const float* __restrict__ w2,
                                              const float* __restrict__ w3,
                                              u16* __restrict__ Wh,
                                              u16* __restrict__ Wl,
                                              u32* __restrict__ zp)
{
  if (blockIdx.x == 0) zp[threadIdx.x] = 0u;    // 1 KB zero page for OOB gload_lds sources
  int i = (blockIdx.x * 256 + threadIdx.x) * 4;
  int z = i >> 16, off = i & 65535;
  const float* w = (z == 0) ? w1 : ((z == 1) ? w2 : w3);
  float4 v = *(const float4*)(w + off);
  u16 h0 = f2bf(v.x), h1 = f2bf(v.y), h2 = f2bf(v.z), h3 = f2bf(v.w);
  u16 l0 = f2bf(v.x - bf2f(h0)), l1 = f2bf(v.y - bf2f(h1));
  u16 l2 = f2bf(v.z - bf2f(h2)), l3 = f2bf(v.w - bf2f(h3));
  uint2 hv; hv.x = (u32)h0 | ((u32)h1 << 16); hv.y = (u32)h2 | ((u32)h3 << 16);
  uint2 lv; lv.x = (u32)l0 | ((u32)l1 << 16); lv.y = (u32)l2 | ((u32)l3 << 16);
  *(uint2*)(Wh + i) = hv;
  *(uint2*)(Wl + i) = lv;
}

// ------- Kernel 1: fused split+qkv. __launch_bounds__(256,4) caps VGPR at 128 ->
// 4 blocks/CU (was ~156 VGPR -> 2 blocks/CU). A staged directly from fp32 x (no
// cross-barrier prefetch); z<2 cross-term MFMAs restructured into two sweeps with
// rolling lo-fragments (live frag VGPR 64->40). Per-acc MFMA order hh->hl->lh
// unchanged -> bit-identical numerics. B via global_load_lds. grid (128,2,3). -------
__global__ __launch_bounds__(256, 4) void qkv_gemm(const float* __restrict__ x,
                                                   const u16* __restrict__ Wh,
                                                   const u16* __restrict__ Wl,
                                                   u16* __restrict__ qh_, u16* __restrict__ ql_,
                                                   u16* __restrict__ kh_, u16* __restrict__ kl_,
                                                   u16* __restrict__ vo)
{
  __shared__ u16 lAh[128 * 32];
  __shared__ u16 lAl[128 * 32];
  __shared__ u16 lBh[128 * 32];
  __shared__ u16 lBl[128 * 32];
  const int z = blockIdx.z;
  const int t = threadIdx.x;
  const int lane = t & 63, wv = t >> 6;
  const int ln15 = lane & 15, q = lane >> 4;
  const int pix0 = blockIdx.x * 128;
  const int o0 = blockIdx.y * 128;
  const int pw = (wv >> 1) * 64, ow = (wv & 1) * 64;
  const int b = pix0 >> 12, hw0 = pix0 & 4095;
  f32x4 acc[4][4];
  #pragma unroll
  for (int i = 0; i < 4; ++i)
    #pragma unroll
    for (int j = 0; j < 4; ++j)
      acc[i][j] = (f32x4){0.f, 0.f, 0.f, 0.f};

  // ---- B staging geometry (R4-proven) ----
  const int Lr = lane >> 2;
  const int cswz = (lane & 3) ^ ((lane >> 3) & 3);
  const int r0 = wv * 32 + Lr;
  const int r1 = wv * 32 + 16 + Lr;
  const int gB0 = z * 65536 + (o0 + r0) * 256 + cswz * 8;
  const int gB1 = z * 65536 + (o0 + r1) * 256 + cswz * 8;
  const int s0 = wv * 1024;
  const int s1 = wv * 1024 + 512;
  const int qsw = (q ^ ((ln15 >> 1) & 3)) * 8;   // B read-side chunk swizzle (u16)

  // ---- A staging geometry: thread owns (channel-quad cq, pixel-quad pq) ----
  const int cq = t >> 5;                         // [0,8): channels 4cq..4cq+3 of K-slice
  const int pq = t & 31;                         // [0,32): pixels 4pq..4pq+3
  const int apw = cq ^ (pq & 7);                 // swizzled u32-pair index (write side)
  const float* xb = x + (b * 256) * 4096 + hw0;  // x[(b*256+c)*4096 + hw]
  u32* lAh32 = (u32*)lAh;
  u32* lAl32 = (u32*)lAl;

  for (int kc8 = 0; kc8 < 8; ++kc8) {
    __syncthreads();                    // previous K-step done reading LDS
    // B stage (fire-and-forget; drains at next barrier)
    __builtin_amdgcn_global_load_lds((const u32*)(Wh + gB0 + kc8 * 32), (u32*)(lBh + s0), 16, 0, 0);
    __builtin_amdgcn_global_load_lds((const u32*)(Wh + gB1 + kc8 * 32), (u32*)(lBh + s1), 16, 0, 0);
    if (z < 2) {
      __builtin_amdgcn_global_load_lds((const u32*)(Wl + gB0 + kc8 * 32), (u32*)(lBl + s0), 16, 0, 0);
      __builtin_amdgcn_global_load_lds((const u32*)(Wl + gB1 + kc8 * 32), (u32*)(lBl + s1), 16, 0, 0);
    }
    // A stage: load fp32 quads (latency hidden by 4 blocks/CU), convert, b64 write
    {
      const float* xk = xb + kc8 * 32 * 4096;
      float4 axv[4];
      #pragma unroll
      for (int jc = 0; jc < 4; ++jc)
        axv[jc] = *(const float4*)(xk + (4 * cq + jc) * 4096 + pq * 4);
      #pragma unroll
      for (int j = 0; j < 4; ++j) {
        const int row = pq * 4 + j;
        const int woff = row * 16 + apw * 2;
        const float v0 = axv[0][j], v1 = axv[1][j], v2 = axv[2][j], v3 = axv[3][j];
        const u16 h0 = f2bf(v0), h1 = f2bf(v1), h2 = f2bf(v2), h3 = f2bf(v3);
        uint2 hw_; hw_.x = (u32)h0 | ((u32)h1 << 16); hw_.y = (u32)h2 | ((u32)h3 << 16);
        *(uint2*)(lAh32 + woff) = hw_;
        if (z < 2) {
          const u16 l0 = f2bf(v0 - bf2f(h0)), l1 = f2bf(v1 - bf2f(h1));
          const u16 l2 = f2bf(v2 - bf2f(h2)), l3 = f2bf(v3 - bf2f(h3));
          uint2 lw_; lw_.x = (u32)l0 | ((u32)l1 << 16); lw_.y = (u32)l2 | ((u32)l3 << 16);
          *(uint2*)(lAl32 + woff) = lw_;
        }
      }
    }
    __syncthreads();                    // tiles visible (gload_lds drained, ds_writes done)
    short8 afh[4], bfh[4];
    #pragma unroll
    for (int i = 0; i < 4; ++i) {
      const int rowA = pw + i * 16 + ln15;
      const int hxr = (rowA >> 2) & 7;
      const int baseA = rowA * 16;
      const uint2 u0 = *(const uint2*)(lAh32 + baseA + ((2 * q) ^ hxr) * 2);
      const uint2 u1 = *(const uint2*)(lAh32 + baseA + ((2 * q + 1) ^ hxr) * 2);
      uint4 uu; uu.x = u0.x; uu.y = u0.y; uu.z = u1.x; uu.w = u1.y;
      afh[i] = __builtin_bit_cast(short8, uu);
    }
    #pragma unroll
    for (int j = 0; j < 4; ++j)
      bfh[j] = *(const short8*)(lBh + (ow + j * 16 + ln15) * 32 + qsw);
    #pragma unroll
    for (int i = 0; i < 4; ++i)
      #pragma unroll
      for (int j = 0; j < 4; ++j)
        acc[i][j] = __builtin_amdgcn_mfma_f32_16x16x32_bf16(afh[i], bfh[j], acc[i][j], 0, 0, 0);
    if (z < 2) {
      // sweep 2a: afh x bfl (rolling bfl fragment, 8 VGPR live)
      #pragma unroll
      for (int j = 0; j < 4; ++j) {
        const short8 bflj = *(const short8*)(lBl + (ow + j * 16 + ln15) * 32 + qsw);
        #pragma unroll
        for (int i = 0; i < 4; ++i)
          acc[i][j] = __builtin_amdgcn_mfma_f32_16x16x32_bf16(afh[i], bflj, acc[i][j], 0, 0, 0);
      }
      // sweep 2b: afl x bfh (rolling afl fragment)
      #pragma unroll
      for (int i = 0; i < 4; ++i) {
        const int rowA = pw + i * 16 + ln15;
        const int hxr = (rowA >> 2) & 7;
        const int baseA = rowA * 16;
        const uint2 u0 = *(const uint2*)(lAl32 + baseA + ((2 * q) ^ hxr) * 2);
        const uint2 u1 = *(const uint2*)(lAl32 + baseA + ((2 * q + 1) ^ hxr) * 2);
        uint4 uu; uu.x = u0.x; uu.y = u0.y; uu.z = u1.x; uu.w = u1.y;
        const short8 afli = __builtin_bit_cast(short8, uu);
        #pragma unroll
        for (int j = 0; j < 4; ++j)
          acc[i][j] = __builtin_amdgcn_mfma_f32_16x16x32_bf16(afli, bfh[j], acc[i][j], 0, 0, 0);
      }
    }
  }

  // D: m(pixel) = pw + i*16 + q*4 + r, n(o) = ow + j*16 + ln15
  if (z == 2) {
    // v: c-major [o][pix]; 4 acc regs = 4 consecutive pixels -> packed uint2 store
    #pragma unroll
    for (int i = 0; i < 4; ++i) {
      int pixb = pix0 + pw + i * 16 + q * 4;
      #pragma unroll
      for (int j = 0; j < 4; ++j) {
        int o = o0 + ow + j * 16 + ln15;
        u32 p0 = (u32)f2bf(acc[i][j][0]) | ((u32)f2bf(acc[i][j][1]) << 16);
        u32 p1 = (u32)f2bf(acc[i][j][2]) | ((u32)f2bf(acc[i][j][3]) << 16);
        uint2 pvv; pvv.x = p0; pvv.y = p1;
        *(uint2*)(vo + o * 16384 + pixb) = pvv;
      }
    }
  } else {
    u16* dsth = (z == 0) ? qh_ : kh_;
    u16* dstl = (z == 0) ? ql_ : kl_;
    #pragma unroll
    for (int i = 0; i < 4; ++i) {
      #pragma unroll
      for (int r = 0; r < 4; ++r) {
        int pix = pix0 + pw + i * 16 + q * 4 + r;
        int ob = o0 + ow + ln15;
        #pragma unroll
        for (int j = 0; j < 4; ++j) {
          float vv = acc[i][j][r];
          u16 hh = f2bf(vv);
          u16 ll = f2bf(vv - bf2f(hh));
          dsth[pix * 256 + ob + j * 16] = hh;
          dstl[pix * 256 + ob + j * 16] = ll;
        }
      }
    }
  }
}

// ------- Kernel 2: banded-MFMA local attention (unchanged from R12). -------
__global__ __launch_bounds__(256, 4) void attn(const u16* __restrict__ qh_,
                                               const u16* __restrict__ ql_,
                                               const u16* __restrict__ kh_,
                                               const u16* __restrict__ kl_,
                                               const u16* __restrict__ vo,
                                               const u16* __restrict__ zp,
                                               float* __restrict__ out)
{
  __shared__ u16 kst[12288];             // 24576 B: k hi @0, k lo @+12288B; q hi@0/lo@+8192B; v @0 (16 KB)
  __shared__ float lg2[2][16][57];       // 7296 B
  __shared__ u16 pb[7][16][40];          // 8960 B   (total 40832 <= 40960 -> 4 blocks/CU)

  const int t = threadIdx.x;
  const int lane = t & 63, wv = t >> 6;
  const int l15 = lane & 15, q4 = lane >> 4;
  const int bid = ((int)blockIdx.x & 7) * 128 + ((int)blockIdx.x >> 3);  // XCD-bijective
  const int quarter = bid & 3;
  const int row = bid >> 2;               // b*64 + h
  const int b = row >> 6, h = row & 63;
  const int wbase = quarter * 16;
  char* sk = (char*)kst;

  for (int i = t; i < 2 * 16 * 57; i += 256) ((float*)lg2)[i] = 0.f;
  for (int i = t; i < 2240; i += 256) ((u32*)pb)[i] = 0u;

  // ---------- q stage: gload_lds, linear dest + inverse-swizzled source ----------
  #pragma unroll
  for (int it = 0; it < 2; ++it) {
    const int px = it * 8 + (t >> 5);
    const int co = (t & 31) ^ fpx(px);
    const int g = (row * 64 + wbase + px) * 256 + co * 8;
    __builtin_amdgcn_global_load_lds((const u32*)(qh_ + g), (u32*)(sk + it * 4096 + wv * 1024), 16, 0, 0);
    __builtin_amdgcn_global_load_lds((const u32*)(ql_ + g), (u32*)(sk + 8192 + it * 4096 + wv * 1024), 16, 0, 0);
  }
  __syncthreads();                       // q landed (vmcnt drained at barrier)

  const int ch = wv >> 1, win = wv & 1;  // wave -> (c-half, n-window)
  // q fragments from LDS (unchanged layout)
  short8 qfh[4], qfl[4];
  #pragma unroll
  for (int u = 0; u < 4; ++u) {
    const int co = (ch * 4 + u) * 4 + q4;
    const int off = swzb(l15, co);
    qfh[u] = *(const short8*)(sk + off);
    qfl[u] = *(const short8*)(sk + 8192 + off);
  }
  __syncthreads();                       // all waves done reading q from sk

  // ---------- phase 1: logits ----------
  const int tidx = win ? (l15 + 12 > 23 ? 23 : l15 + 12) : (l15 - 4 < 0 ? 0 : l15 - 4);
  #pragma unroll 1
  for (int dh = 0; dh < 7; ++dh) {
    const int rdh = h + dh - 3;
    const bool rok = (rdh >= 0) && (rdh < 64);
    const int rp = (b * 64 + (rdh < 0 ? 0 : (rdh > 63 ? 63 : rdh))) * 64;
    // GLOADK(dh): k hi+lo, OOB lanes source the zero page
    #pragma unroll
    for (int it = 0; it < 3; ++it) {
      const int px = it * 8 + (t >> 5);
      const int co = (t & 31) ^ fpx(px);
      const int w = wbase - 4 + px;
      const bool ok = rok && (w >= 0) && (w < 64);
      const int g = (rp + (w < 0 ? 0 : (w > 63 ? 63 : w))) * 256 + co * 8;
      const u16* sh = ok ? kh_ + g : zp;
      const u16* sl = ok ? kl_ + g : zp;
      __builtin_amdgcn_global_load_lds((const u32*)sh, (u32*)(sk + it * 4096 + wv * 1024), 16, 0, 0);
      __builtin_amdgcn_global_load_lds((const u32*)sl, (u32*)(sk + 12288 + it * 4096 + wv * 1024), 16, 0, 0);
    }
    __syncthreads();                     // k landed
    f32x4 a0 = {0.f, 0.f, 0.f, 0.f};
    f32x4 a1 = {0.f, 0.f, 0.f, 0.f};     // split chains for MFMA ILP
    #pragma unroll
    for (int u = 0; u < 4; ++u) {
      const int co = (ch * 4 + u) * 4 + q4;
      const int off = swzb(tidx, co);
      const short8 bh_ = *(const short8*)(sk + off);
      const short8 bl_ = *(const short8*)(sk + 12288 + off);
      a0 = __builtin_amdgcn_mfma_f32_16x16x32_bf16(qfh[u], bh_, a0, 0, 0, 0);
      a1 = __builtin_amdgcn_mfma_f32_16x16x32_bf16(qfh[u], bl_, a1, 0, 0, 0);
      a0 = __builtin_amdgcn_mfma_f32_16x16x32_bf16(qfl[u], bh_, a0, 0, 0, 0);
    }
    // scatter band entries: D col n=l15, row m=q4*4+r; dw = n_w - m_w + 3
    #pragma unroll
    for (int r = 0; r < 4; ++r) {
      const int mloc = q4 * 4 + r;
      const int dw = l15 - mloc - 5 + win * 16;
      if (rok && dw >= 0 && dw < 7) lg2[ch][mloc][dh * 7 + dw] = a0[r] + a1[r];
    }
    __syncthreads();                     // all waves done reading k before next GLOADK
  }

  // ---------- softmax: 16 lanes per pixel (reads lg2/pb only; no sk hazard) ----------
  {
    const int px = t >> 4, sub = t & 15;
    float mx = -3.0e38f;
    for (int i = sub; i < 49; i += 16)
      mx = fmaxf(mx, lg2[0][px][i] + lg2[1][px][i]);
    mx = fmaxf(mx, __shfl_xor(mx, 1));
    mx = fmaxf(mx, __shfl_xor(mx, 2));
    mx = fmaxf(mx, __shfl_xor(mx, 4));
    mx = fmaxf(mx, __shfl_xor(mx, 8));
    float s = 0.f;
    for (int i = sub; i < 49; i += 16) {
      float v = __expf(lg2[0][px][i] + lg2[1][px][i] - mx);
      lg2[0][px][i] = v;                  // stash exp (same-lane RAW only)
      s += v;
    }
    s += __shfl_xor(s, 1);
    s += __shfl_xor(s, 2);
    s += __shfl_xor(s, 4);
    s += __shfl_xor(s, 8);
    const float inv = 1.f / s;
    for (int i = sub; i < 49; i += 16) {
      const int dh7 = i / 7, dw7 = i - dh7 * 7;
      pb[dh7][px][px + 5 + dw7] = f2bf(lg2[0][px][i] * inv);
    }
  }

  // ---------- phase 2: out[c][m'] = sum_n' v[c][n'] * P[m'][n'] ----------
  // v tile [256c][32px], sc-swizzled; staged via gload_lds with inverse-swizzled source.
  f32x4 acc[4];
  #pragma unroll
  for (int i = 0; i < 4; ++i) acc[i] = (f32x4){0.f, 0.f, 0.f, 0.f};
  #pragma unroll 1
  for (int dh = 0; dh < 7; ++dh) {
    const int rdh = h + dh - 3;
    const bool rok2 = (rdh >= 0) && (rdh < 64);
    const int rp = (b * 64 + (rdh < 0 ? 0 : (rdh > 63 ? 63 : rdh))) * 64;
    #pragma unroll
    for (int it = 0; it < 4; ++it) {     // GLOADV(dh)
      const int c = it * 64 + (t >> 2);
      const int sc = (c & 3) ^ ((c >> 2) & 3);
      const int po = (t & 3) ^ sc;
      const int w0 = wbase - 8 + po * 8;
      const bool ok = rok2 && (w0 >= 0) && (w0 <= 56);
      const u16* sv = ok ? vo + c * 16384 + rp + (w0 < 0 ? 0 : (w0 > 56 ? 56 : w0)) : zp;
      __builtin_amdgcn_global_load_lds((const u32*)sv, (u32*)(sk + it * 4096 + wv * 1024), 16, 0, 0);
    }
    __syncthreads();                     // v landed (+ pb visible for dh=0)
    #pragma unroll
    for (int i = 0; i < 4; ++i) {
      const int c = wv * 64 + i * 16 + l15;      // A: m = channel, k-octet = q4
      const int sc = (c & 3) ^ ((c >> 2) & 3);
      const short8 af = *(const short8*)(sk + c * 64 + ((q4 ^ sc) * 16));
      const short8 bf_ = *(const short8*)(&pb[dh][l15][q4 * 8]);
      acc[i] = __builtin_amdgcn_mfma_f32_16x16x32_bf16(af, bf_, acc[i], 0, 0, 0);
    }
    __syncthreads();                     // all waves done reading v before next GLOADV
  }
  #pragma unroll
  for (int i = 0; i < 4; ++i) {
    const int ct = wv * 4 + i;
    // D: row m = channel q4*4+r, col n = pixel l15 -> native [b][c][h][w]
    #pragma unroll
    for (int r = 0; r < 4; ++r)
      out[(b * 256 + ct * 16 + q4 * 4 + r) * 4096 + h * 64 + wbase + l15] = acc[i][r];
  }
}

extern "C" void kernel_launch(void* const* d_in, const int* in_sizes, int n_in,
                              void* d_out, int out_size, void* d_ws, size_t ws_size,
                              hipStream_t stream)
{
  const float* x  = (const float*)d_in[0];
  const float* w1 = (const float*)d_in[1];
  const float* w2 = (const float*)d_in[2];
  const float* w3 = (const float*)d_in[3];
  float* out = (float*)d_out;

  char* ws = (char*)d_ws;
  u16* qh_ = (u16*)ws;                     // 8 MB bf16 hi(q), pixel-major [pix][c]
  u16* ql_ = (u16*)(ws + (8u  << 20));     // 8 MB bf16 lo(q)
  u16* kh_ = (u16*)(ws + (16u << 20));     // 8 MB bf16 hi(k)
  u16* kl_ = (u16*)(ws + (24u << 20));     // 8 MB bf16 lo(k)
  u16* vo  = (u16*)(ws + (32u << 20));     // 8 MB bf16 v, c-major [o][pix]
  u16* Wh  = (u16*)(ws + (40u << 20));     // 384 KB
  u16* Wl  = Wh + 196608;                  // 384 KB
  u32* zp  = (u32*)(ws + (41u << 20));     // 1 KB zero page (zeroed by wsplit)

  wsplit<<<192, 256, 0, stream>>>(w1, w2, w3, Wh, Wl, zp);
  qkv_gemm<<<dim3(128, 2, 3), 256, 0, stream>>>(x, Wh, Wl, qh_, ql_, kh_, kl_, vo);
  attn<<<dim3(1024), 256, 0, stream>>>(qh_, ql_, kh_, kl_, vo, (const u16*)zp, out);
}